// Round 16
// baseline (259.813 us; speedup 1.0000x reference)
//
#include <hip/hip_runtime.h>
#include <hip/hip_bf16.h>

// Pipeline (8 graph nodes):
//  1. k_prep : WlT[512][256] bf16 = transpose(Wl); block 0 zeroes subcurD/S
//  2. k_hist : (1024 thr, int4 edge reads) per-block LDS hist; atomic-reserve
//  3. k_scan : exclusive scan -> contiguous bucket starts startD/startS
//  4. k_place: (1024 thr, int4 edge reads) scatter to bucket-sorted dstbin/srcbin
//  5. k_sortdeg: per bucket: LDS counting-sort -> dsorted + nodeoff; degree ->
//              dinv; a3 = x@W0a, y3 = x@W1a
//  6. k_tgather(P1): atomic-free segmented reduce (8 lanes/node);
//              h1 = relu(a3+t1+b1), h1.w = dinv
//  7. k_tgather(P2): same -> t2r
//  8. k_final: 32 rows/block, 256 thr; h2 -> 16KB bf16 XOR-swizzled panel;
//              phase 2 SOFTWARE-PIPELINED (double-buffered bf/af prefetch,
//              step s+1 issued before step s's MFMAs) -> breaks the 16-step
//              dependent-load chain that pinned this kernel at ~121 us.

#define MAXNB 1024
#define BSH 7
#define BSZ 128
#define SRC_BITS 20
#define SRC_MASK ((1u << SRC_BITS) - 1u)
#define EPB 16384

typedef __attribute__((ext_vector_type(8))) short short8;
typedef __attribute__((ext_vector_type(4))) float f32x4;

static __device__ inline unsigned short f2bf(float f) {
    union { float f; unsigned u; } v; v.f = f;
    unsigned r = (v.u + 0x7fffu + ((v.u >> 16) & 1u)) >> 16;
    return (unsigned short)r;
}

// WlT[c][k] = bf16(Wl[k][c]); also block 0 zeroes the reserve cursors.
__global__ __launch_bounds__(256) void k_prep(const float* __restrict__ Wl,
                                              unsigned short* __restrict__ WlT,
                                              unsigned* __restrict__ subcurD,
                                              unsigned* __restrict__ subcurS) {
    __shared__ float tile[32][33];
    int t = threadIdx.x, tx = t & 31, ty = t >> 5;
    if (blockIdx.x == 0) {
        for (int i = t; i < MAXNB; i += 256) { subcurD[i] = 0u; subcurS[i] = 0u; }
    }
    int kb = (blockIdx.x & 7) * 32;
    int cb = (blockIdx.x >> 3) * 32;
#pragma unroll
    for (int r = 0; r < 4; r++) {
        int k = kb + ty + r * 8;
        tile[ty + r * 8][tx] = Wl[(size_t)k * 512 + cb + tx];
    }
    __syncthreads();
#pragma unroll
    for (int r = 0; r < 4; r++) {
        int c = cb + ty + r * 8;
        WlT[(size_t)c * 256 + kb + tx] = f2bf(tile[tx][ty + r * 8]);
    }
}

__global__ __launch_bounds__(1024) void k_hist(const int* __restrict__ ei, int E, int NB,
                                               unsigned* __restrict__ subcurD,
                                               unsigned* __restrict__ subcurS,
                                               unsigned* __restrict__ baseD,
                                               unsigned* __restrict__ baseS) {
    __shared__ unsigned hD[MAXNB], hS[MAXNB];
    int t = threadIdx.x, blk = blockIdx.x;
    for (int i = t; i < NB; i += 1024) { hD[i] = 0u; hS[i] = 0u; }
    __syncthreads();
    int e0 = blk * EPB, e1 = min(e0 + EPB, E);
    if ((E & 3) == 0) {
        int nv = (e1 - e0) >> 2;
        const int4* s4 = (const int4*)(ei + e0);
        const int4* d4 = (const int4*)(ei + (size_t)E + e0);
        for (int i = t; i < nv; i += 1024) {
            int4 ss = s4[i], dd = d4[i];
            if (ss.x != dd.x) { atomicAdd(&hD[dd.x >> BSH], 1u); atomicAdd(&hS[ss.x >> BSH], 1u); }
            if (ss.y != dd.y) { atomicAdd(&hD[dd.y >> BSH], 1u); atomicAdd(&hS[ss.y >> BSH], 1u); }
            if (ss.z != dd.z) { atomicAdd(&hD[dd.z >> BSH], 1u); atomicAdd(&hS[ss.z >> BSH], 1u); }
            if (ss.w != dd.w) { atomicAdd(&hD[dd.w >> BSH], 1u); atomicAdd(&hS[ss.w >> BSH], 1u); }
        }
        for (int e = e0 + (nv << 2) + t; e < e1; e += 1024) {
            int s = ei[e], d = ei[(size_t)E + e];
            if (s != d) { atomicAdd(&hD[d >> BSH], 1u); atomicAdd(&hS[s >> BSH], 1u); }
        }
    } else {
        for (int e = e0 + t; e < e1; e += 1024) {
            int s = ei[e], d = ei[(size_t)E + e];
            if (s != d) { atomicAdd(&hD[d >> BSH], 1u); atomicAdd(&hS[s >> BSH], 1u); }
        }
    }
    __syncthreads();
    unsigned* bD = baseD + (size_t)blk * NB;
    unsigned* bS = baseS + (size_t)blk * NB;
    for (int i = t; i < NB; i += 1024) {
        unsigned h = hD[i];
        if (h) bD[i] = atomicAdd(&subcurD[i], h);
        h = hS[i];
        if (h) bS[i] = atomicAdd(&subcurS[i], h);
    }
}

__global__ __launch_bounds__(1024) void k_scan(const unsigned* __restrict__ totD,
                                               const unsigned* __restrict__ totS,
                                               unsigned* __restrict__ startD,
                                               unsigned* __restrict__ startS, int NB) {
    __shared__ unsigned a[MAXNB], b[MAXNB];
    int t = threadIdx.x;
    for (int i = t; i < NB; i += 1024) a[i] = totD[i];
    __syncthreads();
    unsigned* s = a; unsigned* d = b;
    for (int off = 1; off < NB; off <<= 1) {
        for (int i = t; i < NB; i += 1024)
            d[i] = s[i] + (i >= off ? s[i - off] : 0u);
        __syncthreads();
        unsigned* tmp = s; s = d; d = tmp;
    }
    for (int i = t; i < NB; i += 1024)
        startD[i] = (i == 0) ? 0u : s[i - 1];
    if (t == 0) startD[NB] = s[NB - 1];
    __syncthreads();
    for (int i = t; i < NB; i += 1024) a[i] = totS[i];
    __syncthreads();
    s = a; d = b;
    for (int off = 1; off < NB; off <<= 1) {
        for (int i = t; i < NB; i += 1024)
            d[i] = s[i] + (i >= off ? s[i - off] : 0u);
        __syncthreads();
        unsigned* tmp = s; s = d; d = tmp;
    }
    for (int i = t; i < NB; i += 1024)
        startS[i] = (i == 0) ? 0u : s[i - 1];
    if (t == 0) startS[NB] = s[NB - 1];
}

__global__ __launch_bounds__(1024) void k_place(const int* __restrict__ ei, int E, int NB,
                                                const unsigned* __restrict__ startD,
                                                const unsigned* __restrict__ startS,
                                                const unsigned* __restrict__ baseD,
                                                const unsigned* __restrict__ baseS,
                                                unsigned* __restrict__ dstbin,
                                                unsigned char* __restrict__ srcbin) {
    __shared__ unsigned oD[MAXNB], oS[MAXNB], cD[MAXNB], cS[MAXNB];
    int t = threadIdx.x, blk = blockIdx.x;
    const unsigned* bD = baseD + (size_t)blk * NB;
    const unsigned* bS = baseS + (size_t)blk * NB;
    for (int i = t; i < NB; i += 1024) {
        oD[i] = startD[i] + bD[i];
        oS[i] = startS[i] + bS[i];
        cD[i] = 0u; cS[i] = 0u;
    }
    __syncthreads();
    int e0 = blk * EPB, e1 = min(e0 + EPB, E);
    if ((E & 3) == 0) {
        int nv = (e1 - e0) >> 2;
        const int4* s4 = (const int4*)(ei + e0);
        const int4* d4 = (const int4*)(ei + (size_t)E + e0);
        for (int i = t; i < nv; i += 1024) {
            int4 ss = s4[i], dd = d4[i];
            int sa[4] = {ss.x, ss.y, ss.z, ss.w};
            int da[4] = {dd.x, dd.y, dd.z, dd.w};
#pragma unroll
            for (int j = 0; j < 4; j++) {
                int s = sa[j], d = da[j];
                if (s != d) {
                    int bk = d >> BSH;
                    unsigned pos = oD[bk] + atomicAdd(&cD[bk], 1u);
                    dstbin[pos] = ((unsigned)(d & (BSZ - 1)) << SRC_BITS) | (unsigned)s;
                    int bs = s >> BSH;
                    unsigned ps = oS[bs] + atomicAdd(&cS[bs], 1u);
                    srcbin[ps] = (unsigned char)(s & (BSZ - 1));
                }
            }
        }
        for (int e = e0 + (nv << 2) + t; e < e1; e += 1024) {
            int s = ei[e], d = ei[(size_t)E + e];
            if (s != d) {
                int bk = d >> BSH;
                unsigned pos = oD[bk] + atomicAdd(&cD[bk], 1u);
                dstbin[pos] = ((unsigned)(d & (BSZ - 1)) << SRC_BITS) | (unsigned)s;
                int bs = s >> BSH;
                unsigned ps = oS[bs] + atomicAdd(&cS[bs], 1u);
                srcbin[ps] = (unsigned char)(s & (BSZ - 1));
            }
        }
    } else {
        for (int e = e0 + t; e < e1; e += 1024) {
            int s = ei[e], d = ei[(size_t)E + e];
            if (s != d) {
                int bk = d >> BSH;
                unsigned pos = oD[bk] + atomicAdd(&cD[bk], 1u);
                dstbin[pos] = ((unsigned)(d & (BSZ - 1)) << SRC_BITS) | (unsigned)s;
                int bs = s >> BSH;
                unsigned ps = oS[bs] + atomicAdd(&cS[bs], 1u);
                srcbin[ps] = (unsigned char)(s & (BSZ - 1));
            }
        }
    }
}

// Merged per-bucket kernel: counting-sort -> dsorted + nodeoff; degree -> dinv;
// a3 = x@W0a, y3 = x@W1a.
__global__ __launch_bounds__(256) void k_sortdeg(
    const unsigned* __restrict__ dstbin, const unsigned* __restrict__ startD,
    unsigned* __restrict__ dsorted, unsigned* __restrict__ nodeoff,
    const unsigned char* __restrict__ srcbin, const unsigned* __restrict__ startS,
    const float* __restrict__ x, const float* __restrict__ W0a,
    const float* __restrict__ W1a, float* __restrict__ dinv,
    float4* __restrict__ a3v, float4* __restrict__ y3v, int N) {
    __shared__ unsigned cnt[BSZ], tmp[BSZ], cur[BSZ];
    __shared__ unsigned cnt4[4][BSZ];
    __shared__ float w0[192], w1[192];
    __shared__ float dl[BSZ];
    int t = threadIdx.x, b = blockIdx.x;
    if (t < 192) { w0[t] = W0a[t]; w1[t] = W1a[t]; }
    if (t < BSZ) cnt[t] = 0u;
    for (int i = t; i < 4 * BSZ; i += 256) ((unsigned*)cnt4)[i] = 0u;
    __syncthreads();
    unsigned d0 = startD[b], d1 = startD[b + 1];
    for (unsigned e = d0 + t; e < d1; e += 256)
        atomicAdd(&cnt[dstbin[e] >> SRC_BITS], 1u);
    unsigned s0 = startS[b], s1 = startS[b + 1];
    int rep = t & 3;
    for (unsigned i = s0 + t; i < s1; i += 256) atomicAdd(&cnt4[rep][srcbin[i]], 1u);
    __syncthreads();
    for (int off = 1; off < BSZ; off <<= 1) {
        if (t < BSZ) tmp[t] = cnt[t] + (t >= off ? cnt[t - off] : 0u);
        __syncthreads();
        if (t < BSZ) cnt[t] = tmp[t];
        __syncthreads();
    }
    if (t <= BSZ) {
        unsigned ex = (t == 0) ? 0u : cnt[t - 1];
        int idx = b * BSZ + t;
        if (idx <= N) nodeoff[idx] = d0 + ex;
        if (t < BSZ) cur[t] = ex;
    }
    __syncthreads();
    for (unsigned e = d0 + t; e < d1; e += 256) {
        unsigned p = dstbin[e];
        unsigned pos = d0 + atomicAdd(&cur[p >> SRC_BITS], 1u);
        dsorted[pos] = p & SRC_MASK;
    }
    if (t < BSZ) {
        unsigned c = cnt4[0][t] + cnt4[1][t] + cnt4[2][t] + cnt4[3][t];
        float dv = c ? rsqrtf((float)c) : 0.f;
        dl[t] = dv;
        int g = b * BSZ + t;
        if (g < N) dinv[g] = dv;
    }
    __syncthreads();
    int q = t & 3;
#pragma unroll
    for (int pass = 0; pass < 2; pass++) {
        int nn = (t >> 2) + pass * 64;
        int node = b * BSZ + nn;
        float acc[6] = {0.f, 0.f, 0.f, 0.f, 0.f, 0.f};
        if (node < N) {
            const float4* xr = (const float4*)(x + (size_t)node * 64 + q * 16);
#pragma unroll
            for (int i = 0; i < 4; i++) {
                float4 v = xr[i];
                float xs[4] = {v.x, v.y, v.z, v.w};
#pragma unroll
                for (int c = 0; c < 4; c++) {
                    int f = q * 16 + i * 4 + c;
                    float xi = xs[c];
                    acc[0] += xi * w0[f * 3 + 0];
                    acc[1] += xi * w0[f * 3 + 1];
                    acc[2] += xi * w0[f * 3 + 2];
                    acc[3] += xi * w1[f * 3 + 0];
                    acc[4] += xi * w1[f * 3 + 1];
                    acc[5] += xi * w1[f * 3 + 2];
                }
            }
        }
#pragma unroll
        for (int m = 1; m < 4; m <<= 1)
#pragma unroll
            for (int j = 0; j < 6; j++) acc[j] += __shfl_xor(acc[j], m, 64);
        if (q == 0 && node < N) {
            a3v[node] = make_float4(acc[0], acc[1], acc[2], 0.f);
            y3v[node] = make_float4(acc[3], acc[4], acc[5], dl[nn]);
        }
    }
}

// Atomic-free segmented gather: 8 lanes/node, 64 nodes per 512-thread block.
__global__ __launch_bounds__(512) void k_tgather(
    const unsigned* __restrict__ dsorted, const unsigned* __restrict__ nodeoff,
    const float4* __restrict__ v4, const float* __restrict__ dinv,
    const float4* __restrict__ a3v, const float* __restrict__ b1,
    float4* __restrict__ outv, int N, int phase) {
    int t = threadIdx.x;
    int g = t >> 3, q = t & 7;
    int node = blockIdx.x * 64 + g;
    if (node >= N) return;
    float dv = dinv[node];
    unsigned o0 = nodeoff[node], o1 = nodeoff[node + 1];
    float s0 = 0.f, s1 = 0.f, s2 = 0.f;
    for (unsigned e = o0 + q; e < o1; e += 8) {
        float4 v = v4[dsorted[e]];
        float nm = -v.w * dv;
        s0 += nm * v.x; s1 += nm * v.y; s2 += nm * v.z;
    }
#pragma unroll
    for (int m = 1; m < 8; m <<= 1) {
        s0 += __shfl_xor(s0, m, 64);
        s1 += __shfl_xor(s1, m, 64);
        s2 += __shfl_xor(s2, m, 64);
    }
    if (q == 0) {
        if (phase == 1) {
            float4 a = a3v[node];
            outv[node] = make_float4(fmaxf(s0 + a.x + b1[0], 0.f),
                                     fmaxf(s1 + a.y + b1[1], 0.f),
                                     fmaxf(s2 + a.z + b1[2], 0.f), dv);
        } else {
            outv[node] = make_float4(s0, s1, s2, 0.f);
        }
    }
}

// 32 rows/block, 256 threads. 16 KB XOR-swizzled panel. Phase 2 is software-
// pipelined: bf (WlT) and af (LDS) for step s+1 are issued before step s's
// MFMAs, double-buffered in registers (all indices compile-time).
__global__ __launch_bounds__(256) void k_final_mfma(
    const float4* __restrict__ h1v, const float4* __restrict__ t2r,
    const float* __restrict__ W0b, const float* __restrict__ W1b,
    const float* __restrict__ b2, const unsigned short* __restrict__ WlT,
    const float* __restrict__ bl, float* __restrict__ out, int N) {
    __shared__ unsigned short h2s[32 * 256];   // 16 KB
    __shared__ float4 u4[32][2];               // 1 KB [h1 | t2]
    char* h2b = (char*)h2s;
    int t = threadIdx.x, b = blockIdx.x;
    int n0 = b * 32;

    if (t < 32) {
        int g = n0 + t;
        u4[t][0] = (g < N) ? h1v[g] : make_float4(0.f, 0.f, 0.f, 0.f);
    } else if (t < 64) {
        int g = n0 + t - 32;
        u4[t - 32][1] = (g < N) ? t2r[g] : make_float4(0.f, 0.f, 0.f, 0.f);
    }
    __syncthreads();

    {   // phase 1: thread -> k pair (t&127)*2, row half (t>>7)*16 .. +15
        int k0 = (t & 127) * 2;
        int rh = (t >> 7) * 16;
        float w00a = W0b[k0],       w00b = W0b[k0 + 1];
        float w01a = W0b[256 + k0], w01b = W0b[256 + k0 + 1];
        float w02a = W0b[512 + k0], w02b = W0b[512 + k0 + 1];
        float w10a = W1b[k0],       w10b = W1b[k0 + 1];
        float w11a = W1b[256 + k0], w11b = W1b[256 + k0 + 1];
        float w12a = W1b[512 + k0], w12b = W1b[512 + k0 + 1];
        float bka = b2[k0], bkb = b2[k0 + 1];
        int kbyte = k0 * 2;
#pragma unroll
        for (int r = 0; r < 16; r++) {
            int rr = rh + r;
            float4 h = u4[rr][0];
            float4 v = u4[rr][1];
            float za = bka + h.x * w00a + h.y * w01a + h.z * w02a
                           + v.x * w10a + v.y * w11a + v.z * w12a;
            float zb = bkb + h.x * w00b + h.y * w01b + h.z * w02b
                           + v.x * w10b + v.y * w11b + v.z * w12b;
            za = fmaxf(za, 0.f); zb = fmaxf(zb, 0.f);
            unsigned pk = ((unsigned)f2bf(zb) << 16) | (unsigned)f2bf(za);
            int byte = rr * 512 + (kbyte ^ ((rr & 7) << 4));
            *(unsigned*)(h2b + byte) = pk;
        }
    }
    __syncthreads();

    // phase 2: wave w -> cols w*128; 16 steps = (ch:2)x(ks:8), pipelined.
    int w = t >> 6, l = t & 63;
    int col0 = w * 128;
    int lrow = l & 15, lkb = (l >> 4) * 8, cq = (l >> 4) * 4;

    short8 bfA[4], bfB[4], afA[2], afB[2];

    auto load_step = [&](int s, short8 (&bf)[4], short8 (&af)[2]) {
        int ch = s >> 3, ks = s & 7;
        int kel = ks * 32 + lkb;
        int cb0 = col0 + ch * 64;
#pragma unroll
        for (int ct = 0; ct < 4; ct++)
            bf[ct] = *(const short8*)(WlT + (size_t)(cb0 + ct * 16 + lrow) * 256 + kel);
#pragma unroll
        for (int rt = 0; rt < 2; rt++) {
            int r = rt * 16 + lrow;
            af[rt] = *(const short8*)(h2b + r * 512 + ((kel * 2) ^ ((r & 7) << 4)));
        }
    };

    auto store_ch = [&](int ch, f32x4 (&acc)[2][4]) {
        int cb0 = col0 + ch * 64;
        f32x4 blv[4];
#pragma unroll
        for (int ct = 0; ct < 4; ct++)
            blv[ct] = *(const f32x4*)(bl + cb0 + ct * 16 + cq);
#pragma unroll
        for (int rt = 0; rt < 2; rt++) {
            int row = n0 + rt * 16 + lrow;
            if (row < N) {
                float* orow = out + (size_t)row * 512 + cb0 + cq;
#pragma unroll
                for (int ct = 0; ct < 4; ct++) {
                    f32x4 sv = acc[rt][ct] + blv[ct];
                    *(f32x4*)(orow + ct * 16) = sv;
                }
            }
        }
#pragma unroll
        for (int rt = 0; rt < 2; rt++)
#pragma unroll
            for (int ct = 0; ct < 4; ct++) acc[rt][ct] = (f32x4)0.f;
    };

    f32x4 acc[2][4];
#pragma unroll
    for (int rt = 0; rt < 2; rt++)
#pragma unroll
        for (int ct = 0; ct < 4; ct++) acc[rt][ct] = (f32x4)0.f;

    load_step(0, bfA, afA);
#pragma unroll
    for (int sp = 0; sp < 8; sp++) {
        // even step 2*sp uses A; prefetch 2*sp+1 into B first
        load_step(2 * sp + 1, bfB, afB);
#pragma unroll
        for (int rt = 0; rt < 2; rt++)
#pragma unroll
            for (int ct = 0; ct < 4; ct++)
                acc[rt][ct] = __builtin_amdgcn_mfma_f32_16x16x32_bf16(
                    bfA[ct], afA[rt], acc[rt][ct], 0, 0, 0);
        // odd step 2*sp+1 uses B; prefetch 2*sp+2 into A first
        if (sp < 7) load_step(2 * sp + 2, bfA, afA);
#pragma unroll
        for (int rt = 0; rt < 2; rt++)
#pragma unroll
            for (int ct = 0; ct < 4; ct++)
                acc[rt][ct] = __builtin_amdgcn_mfma_f32_16x16x32_bf16(
                    bfB[ct], afB[rt], acc[rt][ct], 0, 0, 0);
        if (sp == 3) store_ch(0, acc);   // end of ch 0 (steps 0..7)
        if (sp == 7) store_ch(1, acc);   // end of ch 1 (steps 8..15)
    }
}

extern "C" void kernel_launch(void* const* d_in, const int* in_sizes, int n_in,
                              void* d_out, int out_size, void* d_ws, size_t ws_size,
                              hipStream_t stream) {
    const float* x   = (const float*)d_in[0];
    const int*   ei  = (const int*)d_in[1];
    const float* W0a = (const float*)d_in[2];
    const float* W1a = (const float*)d_in[3];
    const float* b1  = (const float*)d_in[4];
    const float* W0b = (const float*)d_in[5];
    const float* W1b = (const float*)d_in[6];
    const float* b2  = (const float*)d_in[7];
    const float* Wl  = (const float*)d_in[8];
    const float* bl  = (const float*)d_in[9];
    float* out = (float*)d_out;

    const int N = in_sizes[0] / 64;
    const int E = in_sizes[1] / 2;
    const int NB = (N + BSZ - 1) >> BSH;
    const int CB = (E + EPB - 1) / EPB;
    const int NB64 = (N + 63) / 64;
    const int NB32 = (N + 31) / 32;

    char* base = (char*)d_ws;
    size_t off = 0;
    auto alloc = [&](size_t bytes) {
        void* p = base + off;
        off = (off + bytes + 255) & ~(size_t)255;
        return p;
    };
    unsigned* subcurD = (unsigned*)alloc(MAXNB * 4);
    unsigned* subcurS = (unsigned*)alloc(MAXNB * 4);
    unsigned* startD  = (unsigned*)alloc((MAXNB + 1) * 4);
    unsigned* startS  = (unsigned*)alloc((MAXNB + 1) * 4);
    unsigned* baseD   = (unsigned*)alloc((size_t)CB * NB * 4);
    unsigned* baseS   = (unsigned*)alloc((size_t)CB * NB * 4);
    unsigned* dstbin  = (unsigned*)alloc((size_t)E * 4);
    unsigned* dsorted = (unsigned*)alloc((size_t)E * 4);
    unsigned* nodeoff = (unsigned*)alloc((size_t)(N + 1) * 4);
    unsigned char* srcbin = (unsigned char*)alloc((size_t)E);
    float* dinv = (float*)alloc((size_t)N * 4);
    float* a3v  = (float*)alloc((size_t)N * 16);
    float* y3v  = (float*)alloc((size_t)N * 16);
    float* h1v  = (float*)alloc((size_t)N * 16);
    float* t2r  = (float*)alloc((size_t)N * 16);
    unsigned short* WlT = (unsigned short*)alloc(512 * 256 * 2);

    k_prep<<<128, 256, 0, stream>>>(Wl, WlT, subcurD, subcurS);
    k_hist<<<CB, 1024, 0, stream>>>(ei, E, NB, subcurD, subcurS, baseD, baseS);
    k_scan<<<1, 1024, 0, stream>>>(subcurD, subcurS, startD, startS, NB);
    k_place<<<CB, 1024, 0, stream>>>(ei, E, NB, startD, startS, baseD, baseS,
                                     dstbin, srcbin);
    k_sortdeg<<<NB, 256, 0, stream>>>(dstbin, startD, dsorted, nodeoff,
                                      srcbin, startS, x, W0a, W1a, dinv,
                                      (float4*)a3v, (float4*)y3v, N);
    k_tgather<<<NB64, 512, 0, stream>>>(dsorted, nodeoff, (const float4*)y3v, dinv,
                                        (const float4*)a3v, b1, (float4*)h1v, N, 1);
    k_tgather<<<NB64, 512, 0, stream>>>(dsorted, nodeoff, (const float4*)h1v, dinv,
                                        (const float4*)a3v, b1, (float4*)t2r, N, 2);
    k_final_mfma<<<NB32, 256, 0, stream>>>(
        (const float4*)h1v, (const float4*)t2r, W0b, W1b, b2, WlT, bl, out, N);
}

// Round 17
// 219.160 us; speedup vs baseline: 1.1855x; 1.1855x over previous
//
#include <hip/hip_runtime.h>
#include <hip/hip_bf16.h>

// Pipeline (8 graph nodes) — round-13 base (best: 234 us) + column-split k_final:
//  1. k_prep : WlT[512][256] bf16 = transpose(Wl); block 0 zeroes subcurD/S
//  2. k_hist : (1024 thr, int4 edge reads) per-block LDS hist; atomic-reserve
//  3. k_scan : exclusive scan -> contiguous bucket starts startD/startS
//  4. k_place: (1024 thr, int4 edge reads) scatter to bucket-sorted dstbin/srcbin
//  5. k_sortdeg: per bucket: LDS counting-sort -> dsorted + nodeoff; degree ->
//              dinv; a3 = x@W0a, y3 = x@W1a
//  6. k_tgather(P1): atomic-free segmented reduce (8 lanes/node);
//              h1 = relu(a3+t1+b1), h1.w = dinv
//  7. k_tgather(P2): same -> t2r
//  8. k_final: grid (NB64 x 2): 64 rows x 256 cols per block (col half =
//              blockIdx.y), phase-1 h2 panel duplicated per half (cheap);
//              NONTEMPORAL stores (keep WlT hot in L2 — the round-13 win).

#define MAXNB 1024
#define BSH 7
#define BSZ 128
#define SRC_BITS 20
#define SRC_MASK ((1u << SRC_BITS) - 1u)
#define EPB 16384

typedef __attribute__((ext_vector_type(8))) short short8;
typedef __attribute__((ext_vector_type(4))) float f32x4;

static __device__ inline unsigned short f2bf(float f) {
    union { float f; unsigned u; } v; v.f = f;
    unsigned r = (v.u + 0x7fffu + ((v.u >> 16) & 1u)) >> 16;
    return (unsigned short)r;
}

// WlT[c][k] = bf16(Wl[k][c]); also block 0 zeroes the reserve cursors.
__global__ __launch_bounds__(256) void k_prep(const float* __restrict__ Wl,
                                              unsigned short* __restrict__ WlT,
                                              unsigned* __restrict__ subcurD,
                                              unsigned* __restrict__ subcurS) {
    __shared__ float tile[32][33];
    int t = threadIdx.x, tx = t & 31, ty = t >> 5;
    if (blockIdx.x == 0) {
        for (int i = t; i < MAXNB; i += 256) { subcurD[i] = 0u; subcurS[i] = 0u; }
    }
    int kb = (blockIdx.x & 7) * 32;
    int cb = (blockIdx.x >> 3) * 32;
#pragma unroll
    for (int r = 0; r < 4; r++) {
        int k = kb + ty + r * 8;
        tile[ty + r * 8][tx] = Wl[(size_t)k * 512 + cb + tx];
    }
    __syncthreads();
#pragma unroll
    for (int r = 0; r < 4; r++) {
        int c = cb + ty + r * 8;
        WlT[(size_t)c * 256 + kb + tx] = f2bf(tile[tx][ty + r * 8]);
    }
}

__global__ __launch_bounds__(1024) void k_hist(const int* __restrict__ ei, int E, int NB,
                                               unsigned* __restrict__ subcurD,
                                               unsigned* __restrict__ subcurS,
                                               unsigned* __restrict__ baseD,
                                               unsigned* __restrict__ baseS) {
    __shared__ unsigned hD[MAXNB], hS[MAXNB];
    int t = threadIdx.x, blk = blockIdx.x;
    for (int i = t; i < NB; i += 1024) { hD[i] = 0u; hS[i] = 0u; }
    __syncthreads();
    int e0 = blk * EPB, e1 = min(e0 + EPB, E);
    if ((E & 3) == 0) {
        int nv = (e1 - e0) >> 2;
        const int4* s4 = (const int4*)(ei + e0);
        const int4* d4 = (const int4*)(ei + (size_t)E + e0);
        for (int i = t; i < nv; i += 1024) {
            int4 ss = s4[i], dd = d4[i];
            if (ss.x != dd.x) { atomicAdd(&hD[dd.x >> BSH], 1u); atomicAdd(&hS[ss.x >> BSH], 1u); }
            if (ss.y != dd.y) { atomicAdd(&hD[dd.y >> BSH], 1u); atomicAdd(&hS[ss.y >> BSH], 1u); }
            if (ss.z != dd.z) { atomicAdd(&hD[dd.z >> BSH], 1u); atomicAdd(&hS[ss.z >> BSH], 1u); }
            if (ss.w != dd.w) { atomicAdd(&hD[dd.w >> BSH], 1u); atomicAdd(&hS[ss.w >> BSH], 1u); }
        }
        for (int e = e0 + (nv << 2) + t; e < e1; e += 1024) {
            int s = ei[e], d = ei[(size_t)E + e];
            if (s != d) { atomicAdd(&hD[d >> BSH], 1u); atomicAdd(&hS[s >> BSH], 1u); }
        }
    } else {
        for (int e = e0 + t; e < e1; e += 1024) {
            int s = ei[e], d = ei[(size_t)E + e];
            if (s != d) { atomicAdd(&hD[d >> BSH], 1u); atomicAdd(&hS[s >> BSH], 1u); }
        }
    }
    __syncthreads();
    unsigned* bD = baseD + (size_t)blk * NB;
    unsigned* bS = baseS + (size_t)blk * NB;
    for (int i = t; i < NB; i += 1024) {
        unsigned h = hD[i];
        if (h) bD[i] = atomicAdd(&subcurD[i], h);
        h = hS[i];
        if (h) bS[i] = atomicAdd(&subcurS[i], h);
    }
}

__global__ __launch_bounds__(1024) void k_scan(const unsigned* __restrict__ totD,
                                               const unsigned* __restrict__ totS,
                                               unsigned* __restrict__ startD,
                                               unsigned* __restrict__ startS, int NB) {
    __shared__ unsigned a[MAXNB], b[MAXNB];
    int t = threadIdx.x;
    for (int i = t; i < NB; i += 1024) a[i] = totD[i];
    __syncthreads();
    unsigned* s = a; unsigned* d = b;
    for (int off = 1; off < NB; off <<= 1) {
        for (int i = t; i < NB; i += 1024)
            d[i] = s[i] + (i >= off ? s[i - off] : 0u);
        __syncthreads();
        unsigned* tmp = s; s = d; d = tmp;
    }
    for (int i = t; i < NB; i += 1024)
        startD[i] = (i == 0) ? 0u : s[i - 1];
    if (t == 0) startD[NB] = s[NB - 1];
    __syncthreads();
    for (int i = t; i < NB; i += 1024) a[i] = totS[i];
    __syncthreads();
    s = a; d = b;
    for (int off = 1; off < NB; off <<= 1) {
        for (int i = t; i < NB; i += 1024)
            d[i] = s[i] + (i >= off ? s[i - off] : 0u);
        __syncthreads();
        unsigned* tmp = s; s = d; d = tmp;
    }
    for (int i = t; i < NB; i += 1024)
        startS[i] = (i == 0) ? 0u : s[i - 1];
    if (t == 0) startS[NB] = s[NB - 1];
}

__global__ __launch_bounds__(1024) void k_place(const int* __restrict__ ei, int E, int NB,
                                                const unsigned* __restrict__ startD,
                                                const unsigned* __restrict__ startS,
                                                const unsigned* __restrict__ baseD,
                                                const unsigned* __restrict__ baseS,
                                                unsigned* __restrict__ dstbin,
                                                unsigned char* __restrict__ srcbin) {
    __shared__ unsigned oD[MAXNB], oS[MAXNB], cD[MAXNB], cS[MAXNB];
    int t = threadIdx.x, blk = blockIdx.x;
    const unsigned* bD = baseD + (size_t)blk * NB;
    const unsigned* bS = baseS + (size_t)blk * NB;
    for (int i = t; i < NB; i += 1024) {
        oD[i] = startD[i] + bD[i];
        oS[i] = startS[i] + bS[i];
        cD[i] = 0u; cS[i] = 0u;
    }
    __syncthreads();
    int e0 = blk * EPB, e1 = min(e0 + EPB, E);
    if ((E & 3) == 0) {
        int nv = (e1 - e0) >> 2;
        const int4* s4 = (const int4*)(ei + e0);
        const int4* d4 = (const int4*)(ei + (size_t)E + e0);
        for (int i = t; i < nv; i += 1024) {
            int4 ss = s4[i], dd = d4[i];
            int sa[4] = {ss.x, ss.y, ss.z, ss.w};
            int da[4] = {dd.x, dd.y, dd.z, dd.w};
#pragma unroll
            for (int j = 0; j < 4; j++) {
                int s = sa[j], d = da[j];
                if (s != d) {
                    int bk = d >> BSH;
                    unsigned pos = oD[bk] + atomicAdd(&cD[bk], 1u);
                    dstbin[pos] = ((unsigned)(d & (BSZ - 1)) << SRC_BITS) | (unsigned)s;
                    int bs = s >> BSH;
                    unsigned ps = oS[bs] + atomicAdd(&cS[bs], 1u);
                    srcbin[ps] = (unsigned char)(s & (BSZ - 1));
                }
            }
        }
        for (int e = e0 + (nv << 2) + t; e < e1; e += 1024) {
            int s = ei[e], d = ei[(size_t)E + e];
            if (s != d) {
                int bk = d >> BSH;
                unsigned pos = oD[bk] + atomicAdd(&cD[bk], 1u);
                dstbin[pos] = ((unsigned)(d & (BSZ - 1)) << SRC_BITS) | (unsigned)s;
                int bs = s >> BSH;
                unsigned ps = oS[bs] + atomicAdd(&cS[bs], 1u);
                srcbin[ps] = (unsigned char)(s & (BSZ - 1));
            }
        }
    } else {
        for (int e = e0 + t; e < e1; e += 1024) {
            int s = ei[e], d = ei[(size_t)E + e];
            if (s != d) {
                int bk = d >> BSH;
                unsigned pos = oD[bk] + atomicAdd(&cD[bk], 1u);
                dstbin[pos] = ((unsigned)(d & (BSZ - 1)) << SRC_BITS) | (unsigned)s;
                int bs = s >> BSH;
                unsigned ps = oS[bs] + atomicAdd(&cS[bs], 1u);
                srcbin[ps] = (unsigned char)(s & (BSZ - 1));
            }
        }
    }
}

// Merged per-bucket kernel: counting-sort -> dsorted + nodeoff; degree -> dinv;
// a3 = x@W0a, y3 = x@W1a.
__global__ __launch_bounds__(256) void k_sortdeg(
    const unsigned* __restrict__ dstbin, const unsigned* __restrict__ startD,
    unsigned* __restrict__ dsorted, unsigned* __restrict__ nodeoff,
    const unsigned char* __restrict__ srcbin, const unsigned* __restrict__ startS,
    const float* __restrict__ x, const float* __restrict__ W0a,
    const float* __restrict__ W1a, float* __restrict__ dinv,
    float4* __restrict__ a3v, float4* __restrict__ y3v, int N) {
    __shared__ unsigned cnt[BSZ], tmp[BSZ], cur[BSZ];
    __shared__ unsigned cnt4[4][BSZ];
    __shared__ float w0[192], w1[192];
    __shared__ float dl[BSZ];
    int t = threadIdx.x, b = blockIdx.x;
    if (t < 192) { w0[t] = W0a[t]; w1[t] = W1a[t]; }
    if (t < BSZ) cnt[t] = 0u;
    for (int i = t; i < 4 * BSZ; i += 256) ((unsigned*)cnt4)[i] = 0u;
    __syncthreads();
    unsigned d0 = startD[b], d1 = startD[b + 1];
    for (unsigned e = d0 + t; e < d1; e += 256)
        atomicAdd(&cnt[dstbin[e] >> SRC_BITS], 1u);
    unsigned s0 = startS[b], s1 = startS[b + 1];
    int rep = t & 3;
    for (unsigned i = s0 + t; i < s1; i += 256) atomicAdd(&cnt4[rep][srcbin[i]], 1u);
    __syncthreads();
    for (int off = 1; off < BSZ; off <<= 1) {
        if (t < BSZ) tmp[t] = cnt[t] + (t >= off ? cnt[t - off] : 0u);
        __syncthreads();
        if (t < BSZ) cnt[t] = tmp[t];
        __syncthreads();
    }
    if (t <= BSZ) {
        unsigned ex = (t == 0) ? 0u : cnt[t - 1];
        int idx = b * BSZ + t;
        if (idx <= N) nodeoff[idx] = d0 + ex;
        if (t < BSZ) cur[t] = ex;
    }
    __syncthreads();
    for (unsigned e = d0 + t; e < d1; e += 256) {
        unsigned p = dstbin[e];
        unsigned pos = d0 + atomicAdd(&cur[p >> SRC_BITS], 1u);
        dsorted[pos] = p & SRC_MASK;
    }
    if (t < BSZ) {
        unsigned c = cnt4[0][t] + cnt4[1][t] + cnt4[2][t] + cnt4[3][t];
        float dv = c ? rsqrtf((float)c) : 0.f;
        dl[t] = dv;
        int g = b * BSZ + t;
        if (g < N) dinv[g] = dv;
    }
    __syncthreads();
    int q = t & 3;
#pragma unroll
    for (int pass = 0; pass < 2; pass++) {
        int nn = (t >> 2) + pass * 64;
        int node = b * BSZ + nn;
        float acc[6] = {0.f, 0.f, 0.f, 0.f, 0.f, 0.f};
        if (node < N) {
            const float4* xr = (const float4*)(x + (size_t)node * 64 + q * 16);
#pragma unroll
            for (int i = 0; i < 4; i++) {
                float4 v = xr[i];
                float xs[4] = {v.x, v.y, v.z, v.w};
#pragma unroll
                for (int c = 0; c < 4; c++) {
                    int f = q * 16 + i * 4 + c;
                    float xi = xs[c];
                    acc[0] += xi * w0[f * 3 + 0];
                    acc[1] += xi * w0[f * 3 + 1];
                    acc[2] += xi * w0[f * 3 + 2];
                    acc[3] += xi * w1[f * 3 + 0];
                    acc[4] += xi * w1[f * 3 + 1];
                    acc[5] += xi * w1[f * 3 + 2];
                }
            }
        }
#pragma unroll
        for (int m = 1; m < 4; m <<= 1)
#pragma unroll
            for (int j = 0; j < 6; j++) acc[j] += __shfl_xor(acc[j], m, 64);
        if (q == 0 && node < N) {
            a3v[node] = make_float4(acc[0], acc[1], acc[2], 0.f);
            y3v[node] = make_float4(acc[3], acc[4], acc[5], dl[nn]);
        }
    }
}

// Atomic-free segmented gather: 8 lanes/node, 64 nodes per 512-thread block.
__global__ __launch_bounds__(512) void k_tgather(
    const unsigned* __restrict__ dsorted, const unsigned* __restrict__ nodeoff,
    const float4* __restrict__ v4, const float* __restrict__ dinv,
    const float4* __restrict__ a3v, const float* __restrict__ b1,
    float4* __restrict__ outv, int N, int phase) {
    int t = threadIdx.x;
    int g = t >> 3, q = t & 7;
    int node = blockIdx.x * 64 + g;
    if (node >= N) return;
    float dv = dinv[node];
    unsigned o0 = nodeoff[node], o1 = nodeoff[node + 1];
    float s0 = 0.f, s1 = 0.f, s2 = 0.f;
    for (unsigned e = o0 + q; e < o1; e += 8) {
        float4 v = v4[dsorted[e]];
        float nm = -v.w * dv;
        s0 += nm * v.x; s1 += nm * v.y; s2 += nm * v.z;
    }
#pragma unroll
    for (int m = 1; m < 8; m <<= 1) {
        s0 += __shfl_xor(s0, m, 64);
        s1 += __shfl_xor(s1, m, 64);
        s2 += __shfl_xor(s2, m, 64);
    }
    if (q == 0) {
        if (phase == 1) {
            float4 a = a3v[node];
            outv[node] = make_float4(fmaxf(s0 + a.x + b1[0], 0.f),
                                     fmaxf(s1 + a.y + b1[1], 0.f),
                                     fmaxf(s2 + a.z + b1[2], 0.f), dv);
        } else {
            outv[node] = make_float4(s0, s1, s2, 0.f);
        }
    }
}

// Column-split final GEMM: grid (NB64, 2). Block = 64 rows x 256 cols
// (col half = blockIdx.y). Phase 1 computes the full 64x256 h2 panel (32 KB,
// XOR-swizzled) — duplicated across the two column halves (cheap VALU).
// Phase 2: 4 waves x 64 cols, acc[4][4], swapped MFMA; NONTEMPORAL stores.
__global__ __launch_bounds__(256) void k_final_mfma(
    const float4* __restrict__ h1v, const float4* __restrict__ t2r,
    const float* __restrict__ W0b, const float* __restrict__ W1b,
    const float* __restrict__ b2, const unsigned short* __restrict__ WlT,
    const float* __restrict__ bl, float* __restrict__ out, int N) {
    __shared__ unsigned short h2s[64 * 256];   // 32 KB
    __shared__ float4 u4[64][2];               // 2 KB [h1 | t2]
    char* h2b = (char*)h2s;
    int t = threadIdx.x, b = blockIdx.x;
    int n0 = b * 64;

    if (t < 64) {
        int g = n0 + t;
        u4[t][0] = (g < N) ? h1v[g] : make_float4(0.f, 0.f, 0.f, 0.f);
    } else if (t < 128) {
        int g = n0 + t - 64;
        u4[t - 64][1] = (g < N) ? t2r[g] : make_float4(0.f, 0.f, 0.f, 0.f);
    }
    __syncthreads();

    {   // phase 1: thread -> k pair (t&127)*2, row half (t>>7)*32 .. +31
        int k0 = (t & 127) * 2;
        int rh = (t >> 7) * 32;
        float w00a = W0b[k0],       w00b = W0b[k0 + 1];
        float w01a = W0b[256 + k0], w01b = W0b[256 + k0 + 1];
        float w02a = W0b[512 + k0], w02b = W0b[512 + k0 + 1];
        float w10a = W1b[k0],       w10b = W1b[k0 + 1];
        float w11a = W1b[256 + k0], w11b = W1b[256 + k0 + 1];
        float w12a = W1b[512 + k0], w12b = W1b[512 + k0 + 1];
        float bka = b2[k0], bkb = b2[k0 + 1];
        int kbyte = k0 * 2;
#pragma unroll
        for (int r = 0; r < 32; r++) {
            int rr = rh + r;
            float4 h = u4[rr][0];
            float4 v = u4[rr][1];
            float za = bka + h.x * w00a + h.y * w01a + h.z * w02a
                           + v.x * w10a + v.y * w11a + v.z * w12a;
            float zb = bkb + h.x * w00b + h.y * w01b + h.z * w02b
                           + v.x * w10b + v.y * w11b + v.z * w12b;
            za = fmaxf(za, 0.f); zb = fmaxf(zb, 0.f);
            unsigned pk = ((unsigned)f2bf(zb) << 16) | (unsigned)f2bf(za);
            int byte = rr * 512 + (kbyte ^ ((rr & 7) << 4));
            *(unsigned*)(h2b + byte) = pk;
        }
    }
    __syncthreads();

    // phase 2: wave w -> cols blockIdx.y*256 + w*64 (64 cols); acc[4][4]
    int w = t >> 6, l = t & 63;
    int cb0 = (int)blockIdx.y * 256 + w * 64;
    int lrow = l & 15, lkb = (l >> 4) * 8, cq = (l >> 4) * 4;

    f32x4 acc[4][4];
#pragma unroll
    for (int rt = 0; rt < 4; rt++)
#pragma unroll
        for (int ct = 0; ct < 4; ct++) acc[rt][ct] = (f32x4)0.f;

#pragma unroll
    for (int ks = 0; ks < 8; ks++) {
        int kel = ks * 32 + lkb;
        short8 af[4];
#pragma unroll
        for (int rt = 0; rt < 4; rt++) {
            int r = rt * 16 + lrow;
            int byte = r * 512 + ((kel * 2) ^ ((r & 7) << 4));
            af[rt] = *(const short8*)(h2b + byte);
        }
        short8 bf[4];
#pragma unroll
        for (int ct = 0; ct < 4; ct++) {
            int c = cb0 + ct * 16 + lrow;
            bf[ct] = *(const short8*)(WlT + (size_t)c * 256 + kel);
        }
        // swapped: D^T fragments -> lane holds 4 consecutive out cols
#pragma unroll
        for (int rt = 0; rt < 4; rt++)
#pragma unroll
            for (int ct = 0; ct < 4; ct++)
                acc[rt][ct] = __builtin_amdgcn_mfma_f32_16x16x32_bf16(
                    bf[ct], af[rt], acc[rt][ct], 0, 0, 0);
    }

    f32x4 blv[4];
#pragma unroll
    for (int ct = 0; ct < 4; ct++)
        blv[ct] = *(const f32x4*)(bl + cb0 + ct * 16 + cq);
#pragma unroll
    for (int rt = 0; rt < 4; rt++) {
        int row = n0 + rt * 16 + lrow;
        if (row < N) {
            float* orow = out + (size_t)row * 512 + cb0 + cq;
#pragma unroll
            for (int ct = 0; ct < 4; ct++) {
                f32x4 sv = acc[rt][ct] + blv[ct];
                __builtin_nontemporal_store(sv, (f32x4*)(orow + ct * 16));
            }
        }
    }
}

extern "C" void kernel_launch(void* const* d_in, const int* in_sizes, int n_in,
                              void* d_out, int out_size, void* d_ws, size_t ws_size,
                              hipStream_t stream) {
    const float* x   = (const float*)d_in[0];
    const int*   ei  = (const int*)d_in[1];
    const float* W0a = (const float*)d_in[2];
    const float* W1a = (const float*)d_in[3];
    const float* b1  = (const float*)d_in[4];
    const float* W0b = (const float*)d_in[5];
    const float* W1b = (const float*)d_in[6];
    const float* b2  = (const float*)d_in[7];
    const float* Wl  = (const float*)d_in[8];
    const float* bl  = (const float*)d_in[9];
    float* out = (float*)d_out;

    const int N = in_sizes[0] / 64;
    const int E = in_sizes[1] / 2;
    const int NB = (N + BSZ - 1) >> BSH;
    const int CB = (E + EPB - 1) / EPB;
    const int NB64 = (N + 63) / 64;

    char* base = (char*)d_ws;
    size_t off = 0;
    auto alloc = [&](size_t bytes) {
        void* p = base + off;
        off = (off + bytes + 255) & ~(size_t)255;
        return p;
    };
    unsigned* subcurD = (unsigned*)alloc(MAXNB * 4);
    unsigned* subcurS = (unsigned*)alloc(MAXNB * 4);
    unsigned* startD  = (unsigned*)alloc((MAXNB + 1) * 4);
    unsigned* startS  = (unsigned*)alloc((MAXNB + 1) * 4);
    unsigned* baseD   = (unsigned*)alloc((size_t)CB * NB * 4);
    unsigned* baseS   = (unsigned*)alloc((size_t)CB * NB * 4);
    unsigned* dstbin  = (unsigned*)alloc((size_t)E * 4);
    unsigned* dsorted = (unsigned*)alloc((size_t)E * 4);
    unsigned* nodeoff = (unsigned*)alloc((size_t)(N + 1) * 4);
    unsigned char* srcbin = (unsigned char*)alloc((size_t)E);
    float* dinv = (float*)alloc((size_t)N * 4);
    float* a3v  = (float*)alloc((size_t)N * 16);
    float* y3v  = (float*)alloc((size_t)N * 16);
    float* h1v  = (float*)alloc((size_t)N * 16);
    float* t2r  = (float*)alloc((size_t)N * 16);
    unsigned short* WlT = (unsigned short*)alloc(512 * 256 * 2);

    k_prep<<<128, 256, 0, stream>>>(Wl, WlT, subcurD, subcurS);
    k_hist<<<CB, 1024, 0, stream>>>(ei, E, NB, subcurD, subcurS, baseD, baseS);
    k_scan<<<1, 1024, 0, stream>>>(subcurD, subcurS, startD, startS, NB);
    k_place<<<CB, 1024, 0, stream>>>(ei, E, NB, startD, startS, baseD, baseS,
                                     dstbin, srcbin);
    k_sortdeg<<<NB, 256, 0, stream>>>(dstbin, startD, dsorted, nodeoff,
                                      srcbin, startS, x, W0a, W1a, dinv,
                                      (float4*)a3v, (float4*)y3v, N);
    k_tgather<<<NB64, 512, 0, stream>>>(dsorted, nodeoff, (const float4*)y3v, dinv,
                                        (const float4*)a3v, b1, (float4*)h1v, N, 1);
    k_tgather<<<NB64, 512, 0, stream>>>(dsorted, nodeoff, (const float4*)h1v, dinv,
                                        (const float4*)a3v, b1, (float4*)t2r, N, 2);
    k_final_mfma<<<dim3(NB64, 2), 256, 0, stream>>>(
        (const float4*)h1v, (const float4*)t2r, W0b, W1b, b2, WlT, bl, out, N);
}

// Round 18
// 214.093 us; speedup vs baseline: 1.2136x; 1.0237x over previous
//
#include <hip/hip_runtime.h>
#include <hip/hip_bf16.h>

// Pipeline (8 graph nodes) — round-17 base (best: 219 us) + repacked k_final
// epilogue (full-row 1KB NT stores via LDS staging):
//  1. k_prep : WlT[512][256] bf16 = transpose(Wl); block 0 zeroes subcurD/S
//  2. k_hist : (1024 thr, int4 edge reads) per-block LDS hist; atomic-reserve
//  3. k_scan : exclusive scan -> contiguous bucket starts startD/startS
//  4. k_place: (1024 thr, int4 edge reads) scatter to bucket-sorted dstbin/srcbin
//  5. k_sortdeg: per bucket: LDS counting-sort -> dsorted + nodeoff; degree ->
//              dinv; a3 = x@W0a, y3 = x@W1a
//  6. k_tgather(P1): atomic-free segmented reduce (8 lanes/node);
//              h1 = relu(a3+t1+b1), h1.w = dinv
//  7. k_tgather(P2): same -> t2r
//  8. k_final: grid (NB64 x 2): 64 rows x 256 cols per block; h2 panel 32 KB;
//              swapped MFMA; epilogue REPACKS acc through LDS so each wave
//              NT-stores complete 1KB output rows (fixes 64B partial-line
//              store inefficiency that pinned this kernel at ~26% write BW).

#define MAXNB 1024
#define BSH 7
#define BSZ 128
#define SRC_BITS 20
#define SRC_MASK ((1u << SRC_BITS) - 1u)
#define EPB 16384

typedef __attribute__((ext_vector_type(8))) short short8;
typedef __attribute__((ext_vector_type(4))) float f32x4;

static __device__ inline unsigned short f2bf(float f) {
    union { float f; unsigned u; } v; v.f = f;
    unsigned r = (v.u + 0x7fffu + ((v.u >> 16) & 1u)) >> 16;
    return (unsigned short)r;
}

// WlT[c][k] = bf16(Wl[k][c]); also block 0 zeroes the reserve cursors.
__global__ __launch_bounds__(256) void k_prep(const float* __restrict__ Wl,
                                              unsigned short* __restrict__ WlT,
                                              unsigned* __restrict__ subcurD,
                                              unsigned* __restrict__ subcurS) {
    __shared__ float tile[32][33];
    int t = threadIdx.x, tx = t & 31, ty = t >> 5;
    if (blockIdx.x == 0) {
        for (int i = t; i < MAXNB; i += 256) { subcurD[i] = 0u; subcurS[i] = 0u; }
    }
    int kb = (blockIdx.x & 7) * 32;
    int cb = (blockIdx.x >> 3) * 32;
#pragma unroll
    for (int r = 0; r < 4; r++) {
        int k = kb + ty + r * 8;
        tile[ty + r * 8][tx] = Wl[(size_t)k * 512 + cb + tx];
    }
    __syncthreads();
#pragma unroll
    for (int r = 0; r < 4; r++) {
        int c = cb + ty + r * 8;
        WlT[(size_t)c * 256 + kb + tx] = f2bf(tile[tx][ty + r * 8]);
    }
}

__global__ __launch_bounds__(1024) void k_hist(const int* __restrict__ ei, int E, int NB,
                                               unsigned* __restrict__ subcurD,
                                               unsigned* __restrict__ subcurS,
                                               unsigned* __restrict__ baseD,
                                               unsigned* __restrict__ baseS) {
    __shared__ unsigned hD[MAXNB], hS[MAXNB];
    int t = threadIdx.x, blk = blockIdx.x;
    for (int i = t; i < NB; i += 1024) { hD[i] = 0u; hS[i] = 0u; }
    __syncthreads();
    int e0 = blk * EPB, e1 = min(e0 + EPB, E);
    if ((E & 3) == 0) {
        int nv = (e1 - e0) >> 2;
        const int4* s4 = (const int4*)(ei + e0);
        const int4* d4 = (const int4*)(ei + (size_t)E + e0);
        for (int i = t; i < nv; i += 1024) {
            int4 ss = s4[i], dd = d4[i];
            if (ss.x != dd.x) { atomicAdd(&hD[dd.x >> BSH], 1u); atomicAdd(&hS[ss.x >> BSH], 1u); }
            if (ss.y != dd.y) { atomicAdd(&hD[dd.y >> BSH], 1u); atomicAdd(&hS[ss.y >> BSH], 1u); }
            if (ss.z != dd.z) { atomicAdd(&hD[dd.z >> BSH], 1u); atomicAdd(&hS[ss.z >> BSH], 1u); }
            if (ss.w != dd.w) { atomicAdd(&hD[dd.w >> BSH], 1u); atomicAdd(&hS[ss.w >> BSH], 1u); }
        }
        for (int e = e0 + (nv << 2) + t; e < e1; e += 1024) {
            int s = ei[e], d = ei[(size_t)E + e];
            if (s != d) { atomicAdd(&hD[d >> BSH], 1u); atomicAdd(&hS[s >> BSH], 1u); }
        }
    } else {
        for (int e = e0 + t; e < e1; e += 1024) {
            int s = ei[e], d = ei[(size_t)E + e];
            if (s != d) { atomicAdd(&hD[d >> BSH], 1u); atomicAdd(&hS[s >> BSH], 1u); }
        }
    }
    __syncthreads();
    unsigned* bD = baseD + (size_t)blk * NB;
    unsigned* bS = baseS + (size_t)blk * NB;
    for (int i = t; i < NB; i += 1024) {
        unsigned h = hD[i];
        if (h) bD[i] = atomicAdd(&subcurD[i], h);
        h = hS[i];
        if (h) bS[i] = atomicAdd(&subcurS[i], h);
    }
}

__global__ __launch_bounds__(1024) void k_scan(const unsigned* __restrict__ totD,
                                               const unsigned* __restrict__ totS,
                                               unsigned* __restrict__ startD,
                                               unsigned* __restrict__ startS, int NB) {
    __shared__ unsigned a[MAXNB], b[MAXNB];
    int t = threadIdx.x;
    for (int i = t; i < NB; i += 1024) a[i] = totD[i];
    __syncthreads();
    unsigned* s = a; unsigned* d = b;
    for (int off = 1; off < NB; off <<= 1) {
        for (int i = t; i < NB; i += 1024)
            d[i] = s[i] + (i >= off ? s[i - off] : 0u);
        __syncthreads();
        unsigned* tmp = s; s = d; d = tmp;
    }
    for (int i = t; i < NB; i += 1024)
        startD[i] = (i == 0) ? 0u : s[i - 1];
    if (t == 0) startD[NB] = s[NB - 1];
    __syncthreads();
    for (int i = t; i < NB; i += 1024) a[i] = totS[i];
    __syncthreads();
    s = a; d = b;
    for (int off = 1; off < NB; off <<= 1) {
        for (int i = t; i < NB; i += 1024)
            d[i] = s[i] + (i >= off ? s[i - off] : 0u);
        __syncthreads();
        unsigned* tmp = s; s = d; d = tmp;
    }
    for (int i = t; i < NB; i += 1024)
        startS[i] = (i == 0) ? 0u : s[i - 1];
    if (t == 0) startS[NB] = s[NB - 1];
}

__global__ __launch_bounds__(1024) void k_place(const int* __restrict__ ei, int E, int NB,
                                                const unsigned* __restrict__ startD,
                                                const unsigned* __restrict__ startS,
                                                const unsigned* __restrict__ baseD,
                                                const unsigned* __restrict__ baseS,
                                                unsigned* __restrict__ dstbin,
                                                unsigned char* __restrict__ srcbin) {
    __shared__ unsigned oD[MAXNB], oS[MAXNB], cD[MAXNB], cS[MAXNB];
    int t = threadIdx.x, blk = blockIdx.x;
    const unsigned* bD = baseD + (size_t)blk * NB;
    const unsigned* bS = baseS + (size_t)blk * NB;
    for (int i = t; i < NB; i += 1024) {
        oD[i] = startD[i] + bD[i];
        oS[i] = startS[i] + bS[i];
        cD[i] = 0u; cS[i] = 0u;
    }
    __syncthreads();
    int e0 = blk * EPB, e1 = min(e0 + EPB, E);
    if ((E & 3) == 0) {
        int nv = (e1 - e0) >> 2;
        const int4* s4 = (const int4*)(ei + e0);
        const int4* d4 = (const int4*)(ei + (size_t)E + e0);
        for (int i = t; i < nv; i += 1024) {
            int4 ss = s4[i], dd = d4[i];
            int sa[4] = {ss.x, ss.y, ss.z, ss.w};
            int da[4] = {dd.x, dd.y, dd.z, dd.w};
#pragma unroll
            for (int j = 0; j < 4; j++) {
                int s = sa[j], d = da[j];
                if (s != d) {
                    int bk = d >> BSH;
                    unsigned pos = oD[bk] + atomicAdd(&cD[bk], 1u);
                    dstbin[pos] = ((unsigned)(d & (BSZ - 1)) << SRC_BITS) | (unsigned)s;
                    int bs = s >> BSH;
                    unsigned ps = oS[bs] + atomicAdd(&cS[bs], 1u);
                    srcbin[ps] = (unsigned char)(s & (BSZ - 1));
                }
            }
        }
        for (int e = e0 + (nv << 2) + t; e < e1; e += 1024) {
            int s = ei[e], d = ei[(size_t)E + e];
            if (s != d) {
                int bk = d >> BSH;
                unsigned pos = oD[bk] + atomicAdd(&cD[bk], 1u);
                dstbin[pos] = ((unsigned)(d & (BSZ - 1)) << SRC_BITS) | (unsigned)s;
                int bs = s >> BSH;
                unsigned ps = oS[bs] + atomicAdd(&cS[bs], 1u);
                srcbin[ps] = (unsigned char)(s & (BSZ - 1));
            }
        }
    } else {
        for (int e = e0 + t; e < e1; e += 1024) {
            int s = ei[e], d = ei[(size_t)E + e];
            if (s != d) {
                int bk = d >> BSH;
                unsigned pos = oD[bk] + atomicAdd(&cD[bk], 1u);
                dstbin[pos] = ((unsigned)(d & (BSZ - 1)) << SRC_BITS) | (unsigned)s;
                int bs = s >> BSH;
                unsigned ps = oS[bs] + atomicAdd(&cS[bs], 1u);
                srcbin[ps] = (unsigned char)(s & (BSZ - 1));
            }
        }
    }
}

// Merged per-bucket kernel: counting-sort -> dsorted + nodeoff; degree -> dinv;
// a3 = x@W0a, y3 = x@W1a.
__global__ __launch_bounds__(256) void k_sortdeg(
    const unsigned* __restrict__ dstbin, const unsigned* __restrict__ startD,
    unsigned* __restrict__ dsorted, unsigned* __restrict__ nodeoff,
    const unsigned char* __restrict__ srcbin, const unsigned* __restrict__ startS,
    const float* __restrict__ x, const float* __restrict__ W0a,
    const float* __restrict__ W1a, float* __restrict__ dinv,
    float4* __restrict__ a3v, float4* __restrict__ y3v, int N) {
    __shared__ unsigned cnt[BSZ], tmp[BSZ], cur[BSZ];
    __shared__ unsigned cnt4[4][BSZ];
    __shared__ float w0[192], w1[192];
    __shared__ float dl[BSZ];
    int t = threadIdx.x, b = blockIdx.x;
    if (t < 192) { w0[t] = W0a[t]; w1[t] = W1a[t]; }
    if (t < BSZ) cnt[t] = 0u;
    for (int i = t; i < 4 * BSZ; i += 256) ((unsigned*)cnt4)[i] = 0u;
    __syncthreads();
    unsigned d0 = startD[b], d1 = startD[b + 1];
    for (unsigned e = d0 + t; e < d1; e += 256)
        atomicAdd(&cnt[dstbin[e] >> SRC_BITS], 1u);
    unsigned s0 = startS[b], s1 = startS[b + 1];
    int rep = t & 3;
    for (unsigned i = s0 + t; i < s1; i += 256) atomicAdd(&cnt4[rep][srcbin[i]], 1u);
    __syncthreads();
    for (int off = 1; off < BSZ; off <<= 1) {
        if (t < BSZ) tmp[t] = cnt[t] + (t >= off ? cnt[t - off] : 0u);
        __syncthreads();
        if (t < BSZ) cnt[t] = tmp[t];
        __syncthreads();
    }
    if (t <= BSZ) {
        unsigned ex = (t == 0) ? 0u : cnt[t - 1];
        int idx = b * BSZ + t;
        if (idx <= N) nodeoff[idx] = d0 + ex;
        if (t < BSZ) cur[t] = ex;
    }
    __syncthreads();
    for (unsigned e = d0 + t; e < d1; e += 256) {
        unsigned p = dstbin[e];
        unsigned pos = d0 + atomicAdd(&cur[p >> SRC_BITS], 1u);
        dsorted[pos] = p & SRC_MASK;
    }
    if (t < BSZ) {
        unsigned c = cnt4[0][t] + cnt4[1][t] + cnt4[2][t] + cnt4[3][t];
        float dv = c ? rsqrtf((float)c) : 0.f;
        dl[t] = dv;
        int g = b * BSZ + t;
        if (g < N) dinv[g] = dv;
    }
    __syncthreads();
    int q = t & 3;
#pragma unroll
    for (int pass = 0; pass < 2; pass++) {
        int nn = (t >> 2) + pass * 64;
        int node = b * BSZ + nn;
        float acc[6] = {0.f, 0.f, 0.f, 0.f, 0.f, 0.f};
        if (node < N) {
            const float4* xr = (const float4*)(x + (size_t)node * 64 + q * 16);
#pragma unroll
            for (int i = 0; i < 4; i++) {
                float4 v = xr[i];
                float xs[4] = {v.x, v.y, v.z, v.w};
#pragma unroll
                for (int c = 0; c < 4; c++) {
                    int f = q * 16 + i * 4 + c;
                    float xi = xs[c];
                    acc[0] += xi * w0[f * 3 + 0];
                    acc[1] += xi * w0[f * 3 + 1];
                    acc[2] += xi * w0[f * 3 + 2];
                    acc[3] += xi * w1[f * 3 + 0];
                    acc[4] += xi * w1[f * 3 + 1];
                    acc[5] += xi * w1[f * 3 + 2];
                }
            }
        }
#pragma unroll
        for (int m = 1; m < 4; m <<= 1)
#pragma unroll
            for (int j = 0; j < 6; j++) acc[j] += __shfl_xor(acc[j], m, 64);
        if (q == 0 && node < N) {
            a3v[node] = make_float4(acc[0], acc[1], acc[2], 0.f);
            y3v[node] = make_float4(acc[3], acc[4], acc[5], dl[nn]);
        }
    }
}

// Atomic-free segmented gather: 8 lanes/node, 64 nodes per 512-thread block.
__global__ __launch_bounds__(512) void k_tgather(
    const unsigned* __restrict__ dsorted, const unsigned* __restrict__ nodeoff,
    const float4* __restrict__ v4, const float* __restrict__ dinv,
    const float4* __restrict__ a3v, const float* __restrict__ b1,
    float4* __restrict__ outv, int N, int phase) {
    int t = threadIdx.x;
    int g = t >> 3, q = t & 7;
    int node = blockIdx.x * 64 + g;
    if (node >= N) return;
    float dv = dinv[node];
    unsigned o0 = nodeoff[node], o1 = nodeoff[node + 1];
    float s0 = 0.f, s1 = 0.f, s2 = 0.f;
    for (unsigned e = o0 + q; e < o1; e += 8) {
        float4 v = v4[dsorted[e]];
        float nm = -v.w * dv;
        s0 += nm * v.x; s1 += nm * v.y; s2 += nm * v.z;
    }
#pragma unroll
    for (int m = 1; m < 8; m <<= 1) {
        s0 += __shfl_xor(s0, m, 64);
        s1 += __shfl_xor(s1, m, 64);
        s2 += __shfl_xor(s2, m, 64);
    }
    if (q == 0) {
        if (phase == 1) {
            float4 a = a3v[node];
            outv[node] = make_float4(fmaxf(s0 + a.x + b1[0], 0.f),
                                     fmaxf(s1 + a.y + b1[1], 0.f),
                                     fmaxf(s2 + a.z + b1[2], 0.f), dv);
        } else {
            outv[node] = make_float4(s0, s1, s2, 0.f);
        }
    }
}

// Column-split final GEMM: grid (NB64, 2). Block = 64 rows x 256 cols.
// Phase 1: full 64x256 h2 bf16 panel (32 KB, XOR-swizzled), duplicated per
// column half. Phase 2: swapped MFMA, acc[4][4]/wave. Epilogue: repack acc
// through LDS (two 32-row rounds) -> each wave NT-stores complete 1KB rows.
__global__ __launch_bounds__(256) void k_final_mfma(
    const float4* __restrict__ h1v, const float4* __restrict__ t2r,
    const float* __restrict__ W0b, const float* __restrict__ W1b,
    const float* __restrict__ b2, const unsigned short* __restrict__ WlT,
    const float* __restrict__ bl, float* __restrict__ out, int N) {
    __shared__ unsigned short h2s[64 * 256];   // 32 KB (reused as f32 staging)
    __shared__ float4 u4[64][2];               // 2 KB [h1 | t2]
    char* h2b = (char*)h2s;
    int t = threadIdx.x, b = blockIdx.x;
    int n0 = b * 64;

    if (t < 64) {
        int g = n0 + t;
        u4[t][0] = (g < N) ? h1v[g] : make_float4(0.f, 0.f, 0.f, 0.f);
    } else if (t < 128) {
        int g = n0 + t - 64;
        u4[t - 64][1] = (g < N) ? t2r[g] : make_float4(0.f, 0.f, 0.f, 0.f);
    }
    __syncthreads();

    {   // phase 1: thread -> k pair (t&127)*2, row half (t>>7)*32 .. +31
        int k0 = (t & 127) * 2;
        int rh = (t >> 7) * 32;
        float w00a = W0b[k0],       w00b = W0b[k0 + 1];
        float w01a = W0b[256 + k0], w01b = W0b[256 + k0 + 1];
        float w02a = W0b[512 + k0], w02b = W0b[512 + k0 + 1];
        float w10a = W1b[k0],       w10b = W1b[k0 + 1];
        float w11a = W1b[256 + k0], w11b = W1b[256 + k0 + 1];
        float w12a = W1b[512 + k0], w12b = W1b[512 + k0 + 1];
        float bka = b2[k0], bkb = b2[k0 + 1];
        int kbyte = k0 * 2;
#pragma unroll
        for (int r = 0; r < 32; r++) {
            int rr = rh + r;
            float4 h = u4[rr][0];
            float4 v = u4[rr][1];
            float za = bka + h.x * w00a + h.y * w01a + h.z * w02a
                           + v.x * w10a + v.y * w11a + v.z * w12a;
            float zb = bkb + h.x * w00b + h.y * w01b + h.z * w02b
                           + v.x * w10b + v.y * w11b + v.z * w12b;
            za = fmaxf(za, 0.f); zb = fmaxf(zb, 0.f);
            unsigned pk = ((unsigned)f2bf(zb) << 16) | (unsigned)f2bf(za);
            int byte = rr * 512 + (kbyte ^ ((rr & 7) << 4));
            *(unsigned*)(h2b + byte) = pk;
        }
    }
    __syncthreads();

    // phase 2: wave w -> cols blockIdx.y*256 + w*64 (64 cols); acc[4][4]
    int w = t >> 6, l = t & 63;
    int cb0 = (int)blockIdx.y * 256 + w * 64;
    int lrow = l & 15, lkb = (l >> 4) * 8, cq = (l >> 4) * 4;

    f32x4 acc[4][4];
#pragma unroll
    for (int rt = 0; rt < 4; rt++)
#pragma unroll
        for (int ct = 0; ct < 4; ct++) acc[rt][ct] = (f32x4)0.f;

#pragma unroll
    for (int ks = 0; ks < 8; ks++) {
        int kel = ks * 32 + lkb;
        short8 af[4];
#pragma unroll
        for (int rt = 0; rt < 4; rt++) {
            int r = rt * 16 + lrow;
            int byte = r * 512 + ((kel * 2) ^ ((r & 7) << 4));
            af[rt] = *(const short8*)(h2b + byte);
        }
        short8 bf[4];
#pragma unroll
        for (int ct = 0; ct < 4; ct++) {
            int c = cb0 + ct * 16 + lrow;
            bf[ct] = *(const short8*)(WlT + (size_t)c * 256 + kel);
        }
        // swapped: D^T fragments -> lane holds 4 consecutive out cols
#pragma unroll
        for (int rt = 0; rt < 4; rt++)
#pragma unroll
            for (int ct = 0; ct < 4; ct++)
                acc[rt][ct] = __builtin_amdgcn_mfma_f32_16x16x32_bf16(
                    bf[ct], af[rt], acc[rt][ct], 0, 0, 0);
    }

    f32x4 blv[4];
#pragma unroll
    for (int ct = 0; ct < 4; ct++)
        blv[ct] = *(const f32x4*)(bl + cb0 + ct * 16 + cq);

    // epilogue: repack through LDS (two 32-row rounds) -> full-row NT stores.
    // Staging layout: row_local * 1024 bytes, byte ^= (row_local&7)<<4.
    float* sp = (float*)h2s;
#pragma unroll
    for (int rb = 0; rb < 2; rb++) {
        __syncthreads();   // protect h2 panel / previous round
#pragma unroll
        for (int rr = 0; rr < 2; rr++) {
            int rt = rb * 2 + rr;
            int row_local = rr * 16 + lrow;
            int swz = (row_local & 7) << 4;
            int colb = w * 64 + cq;
#pragma unroll
            for (int ct = 0; ct < 4; ct++) {
                int byte = row_local * 1024 + (((colb + ct * 16) * 4) ^ swz);
                f32x4 sv = acc[rt][ct] + blv[ct];
                *(f32x4*)((char*)sp + byte) = sv;
            }
        }
        __syncthreads();
#pragma unroll
        for (int j = 0; j < 8; j++) {
            int f = j * 256 + t;
            int row_local = f >> 6;          // 64 float4s per row
            int col4 = f & 63;
            int swz = (row_local & 7) << 4;
            int byte = row_local * 1024 + ((col4 * 16) ^ swz);
            f32x4 sv = *(const f32x4*)((const char*)sp + byte);
            int row = n0 + rb * 32 + row_local;
            if (row < N) {
                __builtin_nontemporal_store(
                    sv, (f32x4*)(out + (size_t)row * 512 +
                                 (size_t)blockIdx.y * 256 + col4 * 4));
            }
        }
    }
}

extern "C" void kernel_launch(void* const* d_in, const int* in_sizes, int n_in,
                              void* d_out, int out_size, void* d_ws, size_t ws_size,
                              hipStream_t stream) {
    const float* x   = (const float*)d_in[0];
    const int*   ei  = (const int*)d_in[1];
    const float* W0a = (const float*)d_in[2];
    const float* W1a = (const float*)d_in[3];
    const float* b1  = (const float*)d_in[4];
    const float* W0b = (const float*)d_in[5];
    const float* W1b = (const float*)d_in[6];
    const float* b2  = (const float*)d_in[7];
    const float* Wl  = (const float*)d_in[8];
    const float* bl  = (const float*)d_in[9];
    float* out = (float*)d_out;

    const int N = in_sizes[0] / 64;
    const int E = in_sizes[1] / 2;
    const int NB = (N + BSZ - 1) >> BSH;
    const int CB = (E + EPB - 1) / EPB;
    const int NB64 = (N + 63) / 64;

    char* base = (char*)d_ws;
    size_t off = 0;
    auto alloc = [&](size_t bytes) {
        void* p = base + off;
        off = (off + bytes + 255) & ~(size_t)255;
        return p;
    };
    unsigned* subcurD = (unsigned*)alloc(MAXNB * 4);
    unsigned* subcurS = (unsigned*)alloc(MAXNB * 4);
    unsigned* startD  = (unsigned*)alloc((MAXNB + 1) * 4);
    unsigned* startS  = (unsigned*)alloc((MAXNB + 1) * 4);
    unsigned* baseD   = (unsigned*)alloc((size_t)CB * NB * 4);
    unsigned* baseS   = (unsigned*)alloc((size_t)CB * NB * 4);
    unsigned* dstbin  = (unsigned*)alloc((size_t)E * 4);
    unsigned* dsorted = (unsigned*)alloc((size_t)E * 4);
    unsigned* nodeoff = (unsigned*)alloc((size_t)(N + 1) * 4);
    unsigned char* srcbin = (unsigned char*)alloc((size_t)E);
    float* dinv = (float*)alloc((size_t)N * 4);
    float* a3v  = (float*)alloc((size_t)N * 16);
    float* y3v  = (float*)alloc((size_t)N * 16);
    float* h1v  = (float*)alloc((size_t)N * 16);
    float* t2r  = (float*)alloc((size_t)N * 16);
    unsigned short* WlT = (unsigned short*)alloc(512 * 256 * 2);

    k_prep<<<128, 256, 0, stream>>>(Wl, WlT, subcurD, subcurS);
    k_hist<<<CB, 1024, 0, stream>>>(ei, E, NB, subcurD, subcurS, baseD, baseS);
    k_scan<<<1, 1024, 0, stream>>>(subcurD, subcurS, startD, startS, NB);
    k_place<<<CB, 1024, 0, stream>>>(ei, E, NB, startD, startS, baseD, baseS,
                                     dstbin, srcbin);
    k_sortdeg<<<NB, 256, 0, stream>>>(dstbin, startD, dsorted, nodeoff,
                                      srcbin, startS, x, W0a, W1a, dinv,
                                      (float4*)a3v, (float4*)y3v, N);
    k_tgather<<<NB64, 512, 0, stream>>>(dsorted, nodeoff, (const float4*)y3v, dinv,
                                        (const float4*)a3v, b1, (float4*)h1v, N, 1);
    k_tgather<<<NB64, 512, 0, stream>>>(dsorted, nodeoff, (const float4*)h1v, dinv,
                                        (const float4*)a3v, b1, (float4*)t2r, N, 2);
    k_final_mfma<<<dim3(NB64, 2), 256, 0, stream>>>(
        (const float4*)h1v, (const float4*)t2r, W0b, W1b, b2, WlT, bl, out, N);
}

// Round 19
// 210.830 us; speedup vs baseline: 1.2323x; 1.0155x over previous
//
#include <hip/hip_runtime.h>
#include <hip/hip_bf16.h>

// Pipeline (8 graph nodes) — round-18 base (best: 214 us) + finer k_final split
// (grid.y=4) + 2-deep unroll in tgather gather loop:
//  1. k_prep : WlT[512][256] bf16 = transpose(Wl); block 0 zeroes subcurD/S
//  2. k_hist : (1024 thr, int4 edge reads) per-block LDS hist; atomic-reserve
//  3. k_scan : exclusive scan -> contiguous bucket starts startD/startS
//  4. k_place: (1024 thr, int4 edge reads) scatter to bucket-sorted dstbin/srcbin
//  5. k_sortdeg: per bucket: LDS counting-sort -> dsorted + nodeoff; degree ->
//              dinv; a3 = x@W0a, y3 = x@W1a
//  6. k_tgather(P1): atomic-free segmented reduce (8 lanes/node, unroll 2);
//              h1 = relu(a3+t1+b1), h1.w = dinv
//  7. k_tgather(P2): same -> t2r
//  8. k_final: grid (NB64 x 4): 64 rows x 128 cols per block; 32 KB h2 panel
//              (duplicated per column quarter — cheap); swapped MFMA acc[4][2];
//              epilogue repacks acc through LDS -> full-row 1KB NT stores.

#define MAXNB 1024
#define BSH 7
#define BSZ 128
#define SRC_BITS 20
#define SRC_MASK ((1u << SRC_BITS) - 1u)
#define EPB 16384

typedef __attribute__((ext_vector_type(8))) short short8;
typedef __attribute__((ext_vector_type(4))) float f32x4;

static __device__ inline unsigned short f2bf(float f) {
    union { float f; unsigned u; } v; v.f = f;
    unsigned r = (v.u + 0x7fffu + ((v.u >> 16) & 1u)) >> 16;
    return (unsigned short)r;
}

// WlT[c][k] = bf16(Wl[k][c]); also block 0 zeroes the reserve cursors.
__global__ __launch_bounds__(256) void k_prep(const float* __restrict__ Wl,
                                              unsigned short* __restrict__ WlT,
                                              unsigned* __restrict__ subcurD,
                                              unsigned* __restrict__ subcurS) {
    __shared__ float tile[32][33];
    int t = threadIdx.x, tx = t & 31, ty = t >> 5;
    if (blockIdx.x == 0) {
        for (int i = t; i < MAXNB; i += 256) { subcurD[i] = 0u; subcurS[i] = 0u; }
    }
    int kb = (blockIdx.x & 7) * 32;
    int cb = (blockIdx.x >> 3) * 32;
#pragma unroll
    for (int r = 0; r < 4; r++) {
        int k = kb + ty + r * 8;
        tile[ty + r * 8][tx] = Wl[(size_t)k * 512 + cb + tx];
    }
    __syncthreads();
#pragma unroll
    for (int r = 0; r < 4; r++) {
        int c = cb + ty + r * 8;
        WlT[(size_t)c * 256 + kb + tx] = f2bf(tile[tx][ty + r * 8]);
    }
}

__global__ __launch_bounds__(1024) void k_hist(const int* __restrict__ ei, int E, int NB,
                                               unsigned* __restrict__ subcurD,
                                               unsigned* __restrict__ subcurS,
                                               unsigned* __restrict__ baseD,
                                               unsigned* __restrict__ baseS) {
    __shared__ unsigned hD[MAXNB], hS[MAXNB];
    int t = threadIdx.x, blk = blockIdx.x;
    for (int i = t; i < NB; i += 1024) { hD[i] = 0u; hS[i] = 0u; }
    __syncthreads();
    int e0 = blk * EPB, e1 = min(e0 + EPB, E);
    if ((E & 3) == 0) {
        int nv = (e1 - e0) >> 2;
        const int4* s4 = (const int4*)(ei + e0);
        const int4* d4 = (const int4*)(ei + (size_t)E + e0);
        for (int i = t; i < nv; i += 1024) {
            int4 ss = s4[i], dd = d4[i];
            if (ss.x != dd.x) { atomicAdd(&hD[dd.x >> BSH], 1u); atomicAdd(&hS[ss.x >> BSH], 1u); }
            if (ss.y != dd.y) { atomicAdd(&hD[dd.y >> BSH], 1u); atomicAdd(&hS[ss.y >> BSH], 1u); }
            if (ss.z != dd.z) { atomicAdd(&hD[dd.z >> BSH], 1u); atomicAdd(&hS[ss.z >> BSH], 1u); }
            if (ss.w != dd.w) { atomicAdd(&hD[dd.w >> BSH], 1u); atomicAdd(&hS[ss.w >> BSH], 1u); }
        }
        for (int e = e0 + (nv << 2) + t; e < e1; e += 1024) {
            int s = ei[e], d = ei[(size_t)E + e];
            if (s != d) { atomicAdd(&hD[d >> BSH], 1u); atomicAdd(&hS[s >> BSH], 1u); }
        }
    } else {
        for (int e = e0 + t; e < e1; e += 1024) {
            int s = ei[e], d = ei[(size_t)E + e];
            if (s != d) { atomicAdd(&hD[d >> BSH], 1u); atomicAdd(&hS[s >> BSH], 1u); }
        }
    }
    __syncthreads();
    unsigned* bD = baseD + (size_t)blk * NB;
    unsigned* bS = baseS + (size_t)blk * NB;
    for (int i = t; i < NB; i += 1024) {
        unsigned h = hD[i];
        if (h) bD[i] = atomicAdd(&subcurD[i], h);
        h = hS[i];
        if (h) bS[i] = atomicAdd(&subcurS[i], h);
    }
}

__global__ __launch_bounds__(1024) void k_scan(const unsigned* __restrict__ totD,
                                               const unsigned* __restrict__ totS,
                                               unsigned* __restrict__ startD,
                                               unsigned* __restrict__ startS, int NB) {
    __shared__ unsigned a[MAXNB], b[MAXNB];
    int t = threadIdx.x;
    for (int i = t; i < NB; i += 1024) a[i] = totD[i];
    __syncthreads();
    unsigned* s = a; unsigned* d = b;
    for (int off = 1; off < NB; off <<= 1) {
        for (int i = t; i < NB; i += 1024)
            d[i] = s[i] + (i >= off ? s[i - off] : 0u);
        __syncthreads();
        unsigned* tmp = s; s = d; d = tmp;
    }
    for (int i = t; i < NB; i += 1024)
        startD[i] = (i == 0) ? 0u : s[i - 1];
    if (t == 0) startD[NB] = s[NB - 1];
    __syncthreads();
    for (int i = t; i < NB; i += 1024) a[i] = totS[i];
    __syncthreads();
    s = a; d = b;
    for (int off = 1; off < NB; off <<= 1) {
        for (int i = t; i < NB; i += 1024)
            d[i] = s[i] + (i >= off ? s[i - off] : 0u);
        __syncthreads();
        unsigned* tmp = s; s = d; d = tmp;
    }
    for (int i = t; i < NB; i += 1024)
        startS[i] = (i == 0) ? 0u : s[i - 1];
    if (t == 0) startS[NB] = s[NB - 1];
}

__global__ __launch_bounds__(1024) void k_place(const int* __restrict__ ei, int E, int NB,
                                                const unsigned* __restrict__ startD,
                                                const unsigned* __restrict__ startS,
                                                const unsigned* __restrict__ baseD,
                                                const unsigned* __restrict__ baseS,
                                                unsigned* __restrict__ dstbin,
                                                unsigned char* __restrict__ srcbin) {
    __shared__ unsigned oD[MAXNB], oS[MAXNB], cD[MAXNB], cS[MAXNB];
    int t = threadIdx.x, blk = blockIdx.x;
    const unsigned* bD = baseD + (size_t)blk * NB;
    const unsigned* bS = baseS + (size_t)blk * NB;
    for (int i = t; i < NB; i += 1024) {
        oD[i] = startD[i] + bD[i];
        oS[i] = startS[i] + bS[i];
        cD[i] = 0u; cS[i] = 0u;
    }
    __syncthreads();
    int e0 = blk * EPB, e1 = min(e0 + EPB, E);
    if ((E & 3) == 0) {
        int nv = (e1 - e0) >> 2;
        const int4* s4 = (const int4*)(ei + e0);
        const int4* d4 = (const int4*)(ei + (size_t)E + e0);
        for (int i = t; i < nv; i += 1024) {
            int4 ss = s4[i], dd = d4[i];
            int sa[4] = {ss.x, ss.y, ss.z, ss.w};
            int da[4] = {dd.x, dd.y, dd.z, dd.w};
#pragma unroll
            for (int j = 0; j < 4; j++) {
                int s = sa[j], d = da[j];
                if (s != d) {
                    int bk = d >> BSH;
                    unsigned pos = oD[bk] + atomicAdd(&cD[bk], 1u);
                    dstbin[pos] = ((unsigned)(d & (BSZ - 1)) << SRC_BITS) | (unsigned)s;
                    int bs = s >> BSH;
                    unsigned ps = oS[bs] + atomicAdd(&cS[bs], 1u);
                    srcbin[ps] = (unsigned char)(s & (BSZ - 1));
                }
            }
        }
        for (int e = e0 + (nv << 2) + t; e < e1; e += 1024) {
            int s = ei[e], d = ei[(size_t)E + e];
            if (s != d) {
                int bk = d >> BSH;
                unsigned pos = oD[bk] + atomicAdd(&cD[bk], 1u);
                dstbin[pos] = ((unsigned)(d & (BSZ - 1)) << SRC_BITS) | (unsigned)s;
                int bs = s >> BSH;
                unsigned ps = oS[bs] + atomicAdd(&cS[bs], 1u);
                srcbin[ps] = (unsigned char)(s & (BSZ - 1));
            }
        }
    } else {
        for (int e = e0 + t; e < e1; e += 1024) {
            int s = ei[e], d = ei[(size_t)E + e];
            if (s != d) {
                int bk = d >> BSH;
                unsigned pos = oD[bk] + atomicAdd(&cD[bk], 1u);
                dstbin[pos] = ((unsigned)(d & (BSZ - 1)) << SRC_BITS) | (unsigned)s;
                int bs = s >> BSH;
                unsigned ps = oS[bs] + atomicAdd(&cS[bs], 1u);
                srcbin[ps] = (unsigned char)(s & (BSZ - 1));
            }
        }
    }
}

// Merged per-bucket kernel: counting-sort -> dsorted + nodeoff; degree -> dinv;
// a3 = x@W0a, y3 = x@W1a.
__global__ __launch_bounds__(256) void k_sortdeg(
    const unsigned* __restrict__ dstbin, const unsigned* __restrict__ startD,
    unsigned* __restrict__ dsorted, unsigned* __restrict__ nodeoff,
    const unsigned char* __restrict__ srcbin, const unsigned* __restrict__ startS,
    const float* __restrict__ x, const float* __restrict__ W0a,
    const float* __restrict__ W1a, float* __restrict__ dinv,
    float4* __restrict__ a3v, float4* __restrict__ y3v, int N) {
    __shared__ unsigned cnt[BSZ], tmp[BSZ], cur[BSZ];
    __shared__ unsigned cnt4[4][BSZ];
    __shared__ float w0[192], w1[192];
    __shared__ float dl[BSZ];
    int t = threadIdx.x, b = blockIdx.x;
    if (t < 192) { w0[t] = W0a[t]; w1[t] = W1a[t]; }
    if (t < BSZ) cnt[t] = 0u;
    for (int i = t; i < 4 * BSZ; i += 256) ((unsigned*)cnt4)[i] = 0u;
    __syncthreads();
    unsigned d0 = startD[b], d1 = startD[b + 1];
    for (unsigned e = d0 + t; e < d1; e += 256)
        atomicAdd(&cnt[dstbin[e] >> SRC_BITS], 1u);
    unsigned s0 = startS[b], s1 = startS[b + 1];
    int rep = t & 3;
    for (unsigned i = s0 + t; i < s1; i += 256) atomicAdd(&cnt4[rep][srcbin[i]], 1u);
    __syncthreads();
    for (int off = 1; off < BSZ; off <<= 1) {
        if (t < BSZ) tmp[t] = cnt[t] + (t >= off ? cnt[t - off] : 0u);
        __syncthreads();
        if (t < BSZ) cnt[t] = tmp[t];
        __syncthreads();
    }
    if (t <= BSZ) {
        unsigned ex = (t == 0) ? 0u : cnt[t - 1];
        int idx = b * BSZ + t;
        if (idx <= N) nodeoff[idx] = d0 + ex;
        if (t < BSZ) cur[t] = ex;
    }
    __syncthreads();
    for (unsigned e = d0 + t; e < d1; e += 256) {
        unsigned p = dstbin[e];
        unsigned pos = d0 + atomicAdd(&cur[p >> SRC_BITS], 1u);
        dsorted[pos] = p & SRC_MASK;
    }
    if (t < BSZ) {
        unsigned c = cnt4[0][t] + cnt4[1][t] + cnt4[2][t] + cnt4[3][t];
        float dv = c ? rsqrtf((float)c) : 0.f;
        dl[t] = dv;
        int g = b * BSZ + t;
        if (g < N) dinv[g] = dv;
    }
    __syncthreads();
    int q = t & 3;
#pragma unroll
    for (int pass = 0; pass < 2; pass++) {
        int nn = (t >> 2) + pass * 64;
        int node = b * BSZ + nn;
        float acc[6] = {0.f, 0.f, 0.f, 0.f, 0.f, 0.f};
        if (node < N) {
            const float4* xr = (const float4*)(x + (size_t)node * 64 + q * 16);
#pragma unroll
            for (int i = 0; i < 4; i++) {
                float4 v = xr[i];
                float xs[4] = {v.x, v.y, v.z, v.w};
#pragma unroll
                for (int c = 0; c < 4; c++) {
                    int f = q * 16 + i * 4 + c;
                    float xi = xs[c];
                    acc[0] += xi * w0[f * 3 + 0];
                    acc[1] += xi * w0[f * 3 + 1];
                    acc[2] += xi * w0[f * 3 + 2];
                    acc[3] += xi * w1[f * 3 + 0];
                    acc[4] += xi * w1[f * 3 + 1];
                    acc[5] += xi * w1[f * 3 + 2];
                }
            }
        }
#pragma unroll
        for (int m = 1; m < 4; m <<= 1)
#pragma unroll
            for (int j = 0; j < 6; j++) acc[j] += __shfl_xor(acc[j], m, 64);
        if (q == 0 && node < N) {
            a3v[node] = make_float4(acc[0], acc[1], acc[2], 0.f);
            y3v[node] = make_float4(acc[3], acc[4], acc[5], dl[nn]);
        }
    }
}

// Atomic-free segmented gather: 8 lanes/node, 64 nodes per 512-thread block.
__global__ __launch_bounds__(512) void k_tgather(
    const unsigned* __restrict__ dsorted, const unsigned* __restrict__ nodeoff,
    const float4* __restrict__ v4, const float* __restrict__ dinv,
    const float4* __restrict__ a3v, const float* __restrict__ b1,
    float4* __restrict__ outv, int N, int phase) {
    int t = threadIdx.x;
    int g = t >> 3, q = t & 7;
    int node = blockIdx.x * 64 + g;
    if (node >= N) return;
    float dv = dinv[node];
    unsigned o0 = nodeoff[node], o1 = nodeoff[node + 1];
    float s0 = 0.f, s1 = 0.f, s2 = 0.f;
#pragma unroll 2
    for (unsigned e = o0 + q; e < o1; e += 8) {
        float4 v = v4[dsorted[e]];
        float nm = -v.w * dv;
        s0 += nm * v.x; s1 += nm * v.y; s2 += nm * v.z;
    }
#pragma unroll
    for (int m = 1; m < 8; m <<= 1) {
        s0 += __shfl_xor(s0, m, 64);
        s1 += __shfl_xor(s1, m, 64);
        s2 += __shfl_xor(s2, m, 64);
    }
    if (q == 0) {
        if (phase == 1) {
            float4 a = a3v[node];
            outv[node] = make_float4(fmaxf(s0 + a.x + b1[0], 0.f),
                                     fmaxf(s1 + a.y + b1[1], 0.f),
                                     fmaxf(s2 + a.z + b1[2], 0.f), dv);
        } else {
            outv[node] = make_float4(s0, s1, s2, 0.f);
        }
    }
}

// Column-split final GEMM: grid (NB64, 4). Block = 64 rows x 128 cols
// (col quarter = blockIdx.y). Phase 1: full 64x256 h2 panel (32 KB,
// XOR-swizzled), duplicated per quarter (cheap VALU). Phase 2: swapped MFMA,
// acc[4][2]/wave. Epilogue: repack through LDS -> full-row 512B NT stores.
__global__ __launch_bounds__(256) void k_final_mfma(
    const float4* __restrict__ h1v, const float4* __restrict__ t2r,
    const float* __restrict__ W0b, const float* __restrict__ W1b,
    const float* __restrict__ b2, const unsigned short* __restrict__ WlT,
    const float* __restrict__ bl, float* __restrict__ out, int N) {
    __shared__ unsigned short h2s[64 * 256];   // 32 KB (reused as f32 staging)
    __shared__ float4 u4[64][2];               // 2 KB [h1 | t2]
    char* h2b = (char*)h2s;
    int t = threadIdx.x, b = blockIdx.x;
    int n0 = b * 64;

    if (t < 64) {
        int g = n0 + t;
        u4[t][0] = (g < N) ? h1v[g] : make_float4(0.f, 0.f, 0.f, 0.f);
    } else if (t < 128) {
        int g = n0 + t - 64;
        u4[t - 64][1] = (g < N) ? t2r[g] : make_float4(0.f, 0.f, 0.f, 0.f);
    }
    __syncthreads();

    {   // phase 1: thread -> k pair (t&127)*2, row half (t>>7)*32 .. +31
        int k0 = (t & 127) * 2;
        int rh = (t >> 7) * 32;
        float w00a = W0b[k0],       w00b = W0b[k0 + 1];
        float w01a = W0b[256 + k0], w01b = W0b[256 + k0 + 1];
        float w02a = W0b[512 + k0], w02b = W0b[512 + k0 + 1];
        float w10a = W1b[k0],       w10b = W1b[k0 + 1];
        float w11a = W1b[256 + k0], w11b = W1b[256 + k0 + 1];
        float w12a = W1b[512 + k0], w12b = W1b[512 + k0 + 1];
        float bka = b2[k0], bkb = b2[k0 + 1];
        int kbyte = k0 * 2;
#pragma unroll
        for (int r = 0; r < 32; r++) {
            int rr = rh + r;
            float4 h = u4[rr][0];
            float4 v = u4[rr][1];
            float za = bka + h.x * w00a + h.y * w01a + h.z * w02a
                           + v.x * w10a + v.y * w11a + v.z * w12a;
            float zb = bkb + h.x * w00b + h.y * w01b + h.z * w02b
                           + v.x * w10b + v.y * w11b + v.z * w12b;
            za = fmaxf(za, 0.f); zb = fmaxf(zb, 0.f);
            unsigned pk = ((unsigned)f2bf(zb) << 16) | (unsigned)f2bf(za);
            int byte = rr * 512 + (kbyte ^ ((rr & 7) << 4));
            *(unsigned*)(h2b + byte) = pk;
        }
    }
    __syncthreads();

    // phase 2: wave w -> cols blockIdx.y*128 + w*32 (32 cols); acc[4][2]
    int w = t >> 6, l = t & 63;
    int cb0 = (int)blockIdx.y * 128 + w * 32;
    int lrow = l & 15, lkb = (l >> 4) * 8, cq = (l >> 4) * 4;

    f32x4 acc[4][2];
#pragma unroll
    for (int rt = 0; rt < 4; rt++)
#pragma unroll
        for (int ct = 0; ct < 2; ct++) acc[rt][ct] = (f32x4)0.f;

#pragma unroll
    for (int ks = 0; ks < 8; ks++) {
        int kel = ks * 32 + lkb;
        short8 af[4];
#pragma unroll
        for (int rt = 0; rt < 4; rt++) {
            int r = rt * 16 + lrow;
            int byte = r * 512 + ((kel * 2) ^ ((r & 7) << 4));
            af[rt] = *(const short8*)(h2b + byte);
        }
        short8 bf[2];
#pragma unroll
        for (int ct = 0; ct < 2; ct++) {
            int c = cb0 + ct * 16 + lrow;
            bf[ct] = *(const short8*)(WlT + (size_t)c * 256 + kel);
        }
        // swapped: D^T fragments -> lane holds 4 consecutive out cols
#pragma unroll
        for (int rt = 0; rt < 4; rt++)
#pragma unroll
            for (int ct = 0; ct < 2; ct++)
                acc[rt][ct] = __builtin_amdgcn_mfma_f32_16x16x32_bf16(
                    bf[ct], af[rt], acc[rt][ct], 0, 0, 0);
    }

    f32x4 blv[2];
#pragma unroll
    for (int ct = 0; ct < 2; ct++)
        blv[ct] = *(const f32x4*)(bl + cb0 + ct * 16 + cq);

    // epilogue: repack through LDS (two 32-row rounds) -> full 512B-row NT
    // stores. Staging: 32 rows x 128 f32 = 16 KB; row stride 512 B;
    // byte ^= (row&7)<<4 swizzle.
    float* sp = (float*)h2s;
#pragma unroll
    for (int rb = 0; rb < 2; rb++) {
        __syncthreads();   // protect h2 panel / previous round
#pragma unroll
        for (int rr = 0; rr < 2; rr++) {
            int rt = rb * 2 + rr;
            int row_local = rr * 16 + lrow;
            int swz = (row_local & 7) << 4;
            int colb = w * 32 + cq;
#pragma unroll
            for (int ct = 0; ct < 2; ct++) {
                int byte = row_local * 512 + (((colb + ct * 16) * 4) ^ swz);
                f32x4 sv = acc[rt][ct] + blv[ct];
                *(f32x4*)((char*)sp + byte) = sv;
            }
        }
        __syncthreads();
#pragma unroll
        for (int j = 0; j < 4; j++) {
            int f = j * 256 + t;
            int row_local = f >> 5;          // 32 float4s per row
            int col4 = f & 31;
            int swz = (row_local & 7) << 4;
            int byte = row_local * 512 + ((col4 * 16) ^ swz);
            f32x4 sv = *(const f32x4*)((const char*)sp + byte);
            int row = n0 + rb * 32 + row_local;
            if (row < N) {
                __builtin_nontemporal_store(
                    sv, (f32x4*)(out + (size_t)row * 512 +
                                 (size_t)blockIdx.y * 128 + col4 * 4));
            }
        }
    }
}

extern "C" void kernel_launch(void* const* d_in, const int* in_sizes, int n_in,
                              void* d_out, int out_size, void* d_ws, size_t ws_size,
                              hipStream_t stream) {
    const float* x   = (const float*)d_in[0];
    const int*   ei  = (const int*)d_in[1];
    const float* W0a = (const float*)d_in[2];
    const float* W1a = (const float*)d_in[3];
    const float* b1  = (const float*)d_in[4];
    const float* W0b = (const float*)d_in[5];
    const float* W1b = (const float*)d_in[6];
    const float* b2  = (const float*)d_in[7];
    const float* Wl  = (const float*)d_in[8];
    const float* bl  = (const float*)d_in[9];
    float* out = (float*)d_out;

    const int N = in_sizes[0] / 64;
    const int E = in_sizes[1] / 2;
    const int NB = (N + BSZ - 1) >> BSH;
    const int CB = (E + EPB - 1) / EPB;
    const int NB64 = (N + 63) / 64;

    char* base = (char*)d_ws;
    size_t off = 0;
    auto alloc = [&](size_t bytes) {
        void* p = base + off;
        off = (off + bytes + 255) & ~(size_t)255;
        return p;
    };
    unsigned* subcurD = (unsigned*)alloc(MAXNB * 4);
    unsigned* subcurS = (unsigned*)alloc(MAXNB * 4);
    unsigned* startD  = (unsigned*)alloc((MAXNB + 1) * 4);
    unsigned* startS  = (unsigned*)alloc((MAXNB + 1) * 4);
    unsigned* baseD   = (unsigned*)alloc((size_t)CB * NB * 4);
    unsigned* baseS   = (unsigned*)alloc((size_t)CB * NB * 4);
    unsigned* dstbin  = (unsigned*)alloc((size_t)E * 4);
    unsigned* dsorted = (unsigned*)alloc((size_t)E * 4);
    unsigned* nodeoff = (unsigned*)alloc((size_t)(N + 1) * 4);
    unsigned char* srcbin = (unsigned char*)alloc((size_t)E);
    float* dinv = (float*)alloc((size_t)N * 4);
    float* a3v  = (float*)alloc((size_t)N * 16);
    float* y3v  = (float*)alloc((size_t)N * 16);
    float* h1v  = (float*)alloc((size_t)N * 16);
    float* t2r  = (float*)alloc((size_t)N * 16);
    unsigned short* WlT = (unsigned short*)alloc(512 * 256 * 2);

    k_prep<<<128, 256, 0, stream>>>(Wl, WlT, subcurD, subcurS);
    k_hist<<<CB, 1024, 0, stream>>>(ei, E, NB, subcurD, subcurS, baseD, baseS);
    k_scan<<<1, 1024, 0, stream>>>(subcurD, subcurS, startD, startS, NB);
    k_place<<<CB, 1024, 0, stream>>>(ei, E, NB, startD, startS, baseD, baseS,
                                     dstbin, srcbin);
    k_sortdeg<<<NB, 256, 0, stream>>>(dstbin, startD, dsorted, nodeoff,
                                      srcbin, startS, x, W0a, W1a, dinv,
                                      (float4*)a3v, (float4*)y3v, N);
    k_tgather<<<NB64, 512, 0, stream>>>(dsorted, nodeoff, (const float4*)y3v, dinv,
                                        (const float4*)a3v, b1, (float4*)h1v, N, 1);
    k_tgather<<<NB64, 512, 0, stream>>>(dsorted, nodeoff, (const float4*)h1v, dinv,
                                        (const float4*)a3v, b1, (float4*)t2r, N, 2);
    k_final_mfma<<<dim3(NB64, 4), 256, 0, stream>>>(
        (const float4*)h1v, (const float4*)t2r, W0b, W1b, b2, WlT, bl, out, N);
}